// Round 1
// baseline (424.484 us; speedup 1.0000x reference)
//
#include <hip/hip_runtime.h>
#include <stdint.h>
#include <stddef.h>

#define B_ 4
#define L_ 1024
#define D_ 1024
#define H_ 16
#define HD_ 64
#define NROW 65536      // B*L*H
#define QE_LD 132       // qE row stride (bf16 elems)
#define PD_LD 128       // pdiag row stride
#define T_LD 160        // T row stride (= GEMM K, 5 k-tiles of 32)

typedef __attribute__((ext_vector_type(8))) short bf16x8;
typedef __attribute__((ext_vector_type(4))) float f32x4;
typedef __attribute__((ext_vector_type(4))) unsigned short u16x4;

__device__ __forceinline__ float bf2f(unsigned short u) {
  union { unsigned int i; float f; } v; v.i = ((unsigned int)u) << 16; return v.f;
}
__device__ __forceinline__ unsigned short f2bf(float f) {
  union { float f; unsigned int i; } v; v.f = f;
  return (unsigned short)((v.i + 0x7fffu + ((v.i >> 16) & 1u)) >> 16);
}
__device__ __forceinline__ void async16(const void* g, void* l) {
  __builtin_amdgcn_global_load_lds(
      (const __attribute__((address_space(1))) unsigned int*)g,
      (__attribute__((address_space(3))) unsigned int*)l, 16, 0, 0);
}

// ---------------------------------------------------------------------------
// f32 -> bf16 convert (vectorized x4)
// ---------------------------------------------------------------------------
__global__ __launch_bounds__(256) void f32_to_bf16_k(const float* __restrict__ s,
                                                     unsigned short* __restrict__ d, int n4) {
  int i = blockIdx.x * 256 + threadIdx.x;
  int stride = gridDim.x * 256;
  for (; i < n4; i += stride) {
    float4 v = ((const float4*)s)[i];
    u16x4 o;
    o[0] = f2bf(v.x); o[1] = f2bf(v.y); o[2] = f2bf(v.z); o[3] = f2bf(v.w);
    ((u16x4*)d)[i] = o;
  }
}

// Build padded Ek (256x64 bf16, rows>=129 zero) and Ev^T padded (128x160 bf16)
__global__ __launch_bounds__(256) void build_ekev_k(const float* __restrict__ Ek,
                                                    const float* __restrict__ Ev,
                                                    unsigned short* __restrict__ Ekp,
                                                    unsigned short* __restrict__ EvTp) {
  int i = blockIdx.x * 256 + threadIdx.x;
  if (i < 256 * 64) {
    int r = i >> 6, dd = i & 63;
    Ekp[i] = (r < 129) ? f2bf(Ek[r * 64 + dd]) : (unsigned short)0;
  }
  if (i < 128 * 160) {
    int dd = i / 160, r = i - dd * 160;
    EvTp[i] = (dd < 64 && r < 129) ? f2bf(Ev[r * 64 + dd]) : (unsigned short)0;
  }
}

// ---------------------------------------------------------------------------
// GEMM: C[M,N] = A[M,K] * Bt[N,K]^T (+bias) ; bf16 in, f32 acc.
// 128x128 tile, BK=32, 4 waves, chunk-swizzled LDS, global_load_lds x16.
// ---------------------------------------------------------------------------
template<bool OBF16, bool BIAS, bool ACCUM>
__global__ __launch_bounds__(256) void gemm_bt(const unsigned short* __restrict__ A,
                                               const unsigned short* __restrict__ Bt,
                                               const float* __restrict__ bias,
                                               void* __restrict__ Cv,
                                               int lda, int ldb, int ldc, int Ncut, int ktiles) {
  __shared__ unsigned short Al[2][128 * 32];
  __shared__ unsigned short Bl[2][128 * 32];
  const int tid = threadIdx.x;
  const int w = tid >> 6, l = tid & 63;
  const int l15 = l & 15, lg = l >> 4;
  const int row0 = blockIdx.x * 128, col0 = blockIdx.y * 128;
  const int wm = (w >> 1) * 64, wn = (w & 1) * 64;

  f32x4 acc[4][4];
#pragma unroll
  for (int i = 0; i < 4; ++i)
#pragma unroll
    for (int j = 0; j < 4; ++j) acc[i][j] = {0.f, 0.f, 0.f, 0.f};

  auto stage = [&](int buf, int kt) {
#pragma unroll
    for (int i = 0; i < 2; ++i) {
      int p = (i * 4 + w) * 1024 + l * 16;   // byte offset within 8KB tile
      int m = p >> 6;                        // tile-local row (64B rows)
      int clog = (l & 3) ^ ((m >> 1) & 3);   // logical k-chunk for this slot
      async16(A + (size_t)(row0 + m) * lda + kt * 32 + clog * 8,
              (char*)&Al[buf][0] + (i * 4 + w) * 1024);
      async16(Bt + (size_t)(col0 + m) * ldb + kt * 32 + clog * 8,
              (char*)&Bl[buf][0] + (i * 4 + w) * 1024);
    }
  };

  stage(0, 0);
  __syncthreads();
  for (int kt = 0; kt < ktiles; ++kt) {
    int cur = kt & 1;
    if (kt + 1 < ktiles) stage(cur ^ 1, kt + 1);
    bf16x8 af[4], bfr[4];
#pragma unroll
    for (int mi = 0; mi < 4; ++mi) {
      int m = wm + mi * 16 + l15;
      af[mi] = *(const bf16x8*)&Al[cur][m * 32 + ((lg ^ ((m >> 1) & 3)) << 3)];
    }
#pragma unroll
    for (int ni = 0; ni < 4; ++ni) {
      int n = wn + ni * 16 + l15;
      bfr[ni] = *(const bf16x8*)&Bl[cur][n * 32 + ((lg ^ ((n >> 1) & 3)) << 3)];
    }
#pragma unroll
    for (int mi = 0; mi < 4; ++mi)
#pragma unroll
      for (int ni = 0; ni < 4; ++ni)
        acc[mi][ni] = __builtin_amdgcn_mfma_f32_16x16x32_bf16(af[mi], bfr[ni], acc[mi][ni], 0, 0, 0);
    __syncthreads();
  }

#pragma unroll
  for (int ni = 0; ni < 4; ++ni) {
    int col = col0 + wn + ni * 16 + l15;
    if (col < Ncut) {
      float bv = BIAS ? bias[col] : 0.f;
#pragma unroll
      for (int mi = 0; mi < 4; ++mi) {
        int rowb = row0 + wm + mi * 16 + lg * 4;
#pragma unroll
        for (int r = 0; r < 4; ++r) {
          float v = acc[mi][ni][r] + bv;
          size_t off = (size_t)(rowb + r) * ldc + col;
          if (ACCUM) v += bf2f(((const unsigned short*)Cv)[off]);
          if (OBF16) ((unsigned short*)Cv)[off] = f2bf(v);
          else       ((float*)Cv)[off] = v;
        }
      }
    }
  }
}

// ---------------------------------------------------------------------------
// Transpose vp (B,L,H,HD) -> vpT (B,H,HD,L), bf16
// ---------------------------------------------------------------------------
__global__ __launch_bounds__(256) void transpose_v_k(const unsigned short* __restrict__ vp,
                                                     unsigned short* __restrict__ vpT) {
  const int lt = blockIdx.x, bh = blockIdx.y;
  const int b = bh >> 4, h = bh & 15;
  __shared__ unsigned short tile[64][72];
  const int t = threadIdx.x;
#pragma unroll
  for (int j = 0; j < 2; ++j) {
    int lrow = (t >> 3) + 32 * j;
    int d0 = (t & 7) * 8;
    bf16x8 v = *(const bf16x8*)(vp + ((size_t)((b * L_ + lt * 64 + lrow) * H_ + h)) * HD_ + d0);
#pragma unroll
    for (int e = 0; e < 8; ++e) tile[lrow][d0 + e] = (unsigned short)v[e];
  }
  __syncthreads();
#pragma unroll
  for (int j = 0; j < 2; ++j) {
    int d = (t >> 3) + 32 * j;
    int l0 = (t & 7) * 8;
    bf16x8 o;
#pragma unroll
    for (int e = 0; e < 8; ++e) o[e] = (short)tile[l0 + e][d];
    *(bf16x8*)(vpT + ((size_t)((b * H_ + h) * HD_ + d)) * L_ + lt * 64 + l0) = o;
  }
}

// ---------------------------------------------------------------------------
// Fused flash attention with relative-position logits.
// Grid (8 qtiles, 64 bh), 256 thr = 4 waves, Q-tile 128 (32/wave), KV-tile 64.
// Writes: tmp (out1 normalized, bf16), pdiag (band p unnormalized, bf16),
//         m_used (per (row, ktile) running max), mstat/lstat/t0stat.
// ---------------------------------------------------------------------------
__global__ __launch_bounds__(256) void flash_fwd_k(
    const unsigned short* __restrict__ qp, const unsigned short* __restrict__ kp,
    const unsigned short* __restrict__ vpT, const unsigned short* __restrict__ qE,
    unsigned short* __restrict__ pdiag, float* __restrict__ m_used,
    float* __restrict__ mstat, float* __restrict__ lstat, float* __restrict__ t0stat,
    unsigned short* __restrict__ tmp) {
  __shared__ unsigned short Kl[2][64 * 64];
  __shared__ unsigned short Vl[2][64 * 64];
  __shared__ unsigned short Pl[4][32 * 64];
  const int tid = threadIdx.x, w = tid >> 6, l = tid & 63;
  const int l15 = l & 15, lg = l >> 4;
  const int qt = blockIdx.x, bh = blockIdx.y;
  const int b = bh >> 4, h = bh & 15;
  const int qw = qt * 128 + w * 32;
  const float L2E = 1.44269504f;

  // Q fragments in registers: [mi][ks] ; row = qw+mi*16+l15, d = ks*32+lg*8..
  bf16x8 qf[2][2];
#pragma unroll
  for (int mi = 0; mi < 2; ++mi) {
    const unsigned short* qrp = qp + ((size_t)((b * L_ + (qw + mi * 16 + l15)) * H_ + h)) * HD_;
#pragma unroll
    for (int ks = 0; ks < 2; ++ks) qf[mi][ks] = *(const bf16x8*)(qrp + ks * 32 + lg * 8);
  }
  int rowi[2][4];
  float qe0[2][4], qe128[2][4];
#pragma unroll
  for (int mi = 0; mi < 2; ++mi)
#pragma unroll
    for (int r = 0; r < 4; ++r) {
      int q = qw + mi * 16 + lg * 4 + r;
      rowi[mi][r] = (b * L_ + q) * H_ + h;
      const unsigned short* qe = qE + (size_t)rowi[mi][r] * QE_LD;
      qe0[mi][r] = bf2f(qe[0]);
      qe128[mi][r] = bf2f(qe[128]);
    }

  f32x4 O[2][4];
#pragma unroll
  for (int mi = 0; mi < 2; ++mi)
#pragma unroll
    for (int nd = 0; nd < 4; ++nd) O[mi][nd] = {0.f, 0.f, 0.f, 0.f};
  float mrow[2][4], lrow[2][4], t0row[2][4];
#pragma unroll
  for (int mi = 0; mi < 2; ++mi)
#pragma unroll
    for (int r = 0; r < 4; ++r) { mrow[mi][r] = -1e30f; lrow[mi][r] = 0.f; t0row[mi][r] = 0.f; }

  auto stage = [&](int buf, int kt) {
#pragma unroll
    for (int i = 0; i < 2; ++i) {
      int p = (i * 4 + w) * 1024 + l * 16;  // byte in 8KB tile (rows = 128B)
      int row = p >> 7;
      int clog = (l & 7) ^ (row & 7);
      async16(kp + ((size_t)((b * L_ + kt * 64 + row) * H_ + h)) * HD_ + clog * 8,
              (char*)&Kl[buf][0] + (i * 4 + w) * 1024);
      async16(vpT + ((size_t)((b * H_ + h) * HD_ + row)) * L_ + kt * 64 + clog * 8,
              (char*)&Vl[buf][0] + (i * 4 + w) * 1024);
    }
  };

  stage(0, 0);
  __syncthreads();

  for (int kt = 0; kt < 16; ++kt) {
    int cur = kt & 1;
    if (kt + 1 < 16) stage(cur ^ 1, kt + 1);

    // S = Q * K^T  (S[mi][ni], lane: col kk=ni*16+l15, rows q=..lg*4+r)
    f32x4 S[2][4];
#pragma unroll
    for (int mi = 0; mi < 2; ++mi)
#pragma unroll
      for (int ni = 0; ni < 4; ++ni) S[mi][ni] = {0.f, 0.f, 0.f, 0.f};
#pragma unroll
    for (int ks = 0; ks < 2; ++ks) {
      bf16x8 kf[4];
#pragma unroll
      for (int ni = 0; ni < 4; ++ni) {
        int kk = ni * 16 + l15;
        kf[ni] = *(const bf16x8*)&Kl[cur][kk * 64 + (((ks * 4 + lg) ^ (kk & 7)) << 3)];
      }
#pragma unroll
      for (int mi = 0; mi < 2; ++mi)
#pragma unroll
        for (int ni = 0; ni < 4; ++ni)
          S[mi][ni] = __builtin_amdgcn_mfma_f32_16x16x32_bf16(qf[mi][ks], kf[ni], S[mi][ni], 0, 0, 0);
    }

    // relative logits + scale + online softmax
    float alpha[2][4];
#pragma unroll
    for (int mi = 0; mi < 2; ++mi) {
#pragma unroll
      for (int r = 0; r < 4; ++r) {
        int q = qw + mi * 16 + lg * 4 + r;
        const unsigned short* qerow = qE + (size_t)rowi[mi][r] * QE_LD;
        float sv[4];
#pragma unroll
        for (int ni = 0; ni < 4; ++ni) {
          int kg = kt * 64 + ni * 16 + l15;
          int delta = kg - q;
          float qe;
          if (delta >= 64) qe = qe128[mi][r];
          else if (delta <= -64) qe = qe0[mi][r];
          else qe = bf2f(qerow[delta + 64]);
          sv[ni] = (S[mi][ni][r] + qe) * 0.125f;
        }
        float vmax = fmaxf(fmaxf(sv[0], sv[1]), fmaxf(sv[2], sv[3]));
        vmax = fmaxf(vmax, __shfl_xor(vmax, 1));
        vmax = fmaxf(vmax, __shfl_xor(vmax, 2));
        vmax = fmaxf(vmax, __shfl_xor(vmax, 4));
        vmax = fmaxf(vmax, __shfl_xor(vmax, 8));
        float mold = mrow[mi][r];
        float mnew = fmaxf(mold, vmax);
        float a = __builtin_amdgcn_exp2f((mold - mnew) * L2E);
        alpha[mi][r] = a;
        mrow[mi][r] = mnew;
        float ps = 0.f, ps0 = 0.f;
#pragma unroll
        for (int ni = 0; ni < 4; ++ni) {
          float p = __builtin_amdgcn_exp2f((sv[ni] - mnew) * L2E);
          S[mi][ni][r] = p;
          ps += p;
          int kg = kt * 64 + ni * 16 + l15;
          int delta = kg - q;
          if (kg <= q - 64) ps0 += p;
          if (delta > -64 && delta < 64)
            pdiag[(size_t)rowi[mi][r] * PD_LD + (delta + 63)] = f2bf(p);
        }
        ps += __shfl_xor(ps, 1); ps += __shfl_xor(ps, 2);
        ps += __shfl_xor(ps, 4); ps += __shfl_xor(ps, 8);
        ps0 += __shfl_xor(ps0, 1); ps0 += __shfl_xor(ps0, 2);
        ps0 += __shfl_xor(ps0, 4); ps0 += __shfl_xor(ps0, 8);
        lrow[mi][r] = lrow[mi][r] * a + ps;
        t0row[mi][r] = t0row[mi][r] * a + ps0;
        if (l15 == 0) {
          if (kt * 64 <= q + 63 && kt * 64 + 63 >= q - 63)
            m_used[(size_t)rowi[mi][r] * 16 + kt] = mnew;
        }
      }
    }

    // rescale O
#pragma unroll
    for (int mi = 0; mi < 2; ++mi)
#pragma unroll
      for (int nd = 0; nd < 4; ++nd)
#pragma unroll
        for (int r = 0; r < 4; ++r) O[mi][nd][r] *= alpha[mi][r];

    // write P (bf16) to per-wave LDS, chunk-XOR-swizzled rows of 128B
#pragma unroll
    for (int mi = 0; mi < 2; ++mi)
#pragma unroll
      for (int ni = 0; ni < 4; ++ni)
#pragma unroll
        for (int r = 0; r < 4; ++r) {
          int qloc = mi * 16 + lg * 4 + r;
          int kk = ni * 16 + l15;
          Pl[w][qloc * 64 + ((((kk >> 3) ^ (qloc & 7)) << 3) | (kk & 7))] = f2bf(S[mi][ni][r]);
        }
    __syncthreads();

    // O += P * V
#pragma unroll
    for (int ks = 0; ks < 2; ++ks) {
      bf16x8 pf[2];
#pragma unroll
      for (int mi = 0; mi < 2; ++mi) {
        int qloc = mi * 16 + l15;
        pf[mi] = *(const bf16x8*)&Pl[w][qloc * 64 + (((ks * 4 + lg) ^ (qloc & 7)) << 3)];
      }
      bf16x8 vf[4];
#pragma unroll
      for (int nd = 0; nd < 4; ++nd) {
        int d = nd * 16 + l15;
        vf[nd] = *(const bf16x8*)&Vl[cur][d * 64 + (((ks * 4 + lg) ^ (d & 7)) << 3)];
      }
#pragma unroll
      for (int mi = 0; mi < 2; ++mi)
#pragma unroll
        for (int nd = 0; nd < 4; ++nd)
          O[mi][nd] = __builtin_amdgcn_mfma_f32_16x16x32_bf16(pf[mi], vf[nd], O[mi][nd], 0, 0, 0);
    }
    __syncthreads();
  }

  // epilogue: normalize + store out1; stats
#pragma unroll
  for (int mi = 0; mi < 2; ++mi)
#pragma unroll
    for (int r = 0; r < 4; ++r) {
      float inv = 1.f / lrow[mi][r];
      if (l15 == 0) {
        mstat[rowi[mi][r]] = mrow[mi][r];
        lstat[rowi[mi][r]] = lrow[mi][r];
        t0stat[rowi[mi][r]] = t0row[mi][r];
      }
#pragma unroll
      for (int nd = 0; nd < 4; ++nd)
        tmp[(size_t)rowi[mi][r] * HD_ + nd * 16 + l15] = f2bf(O[mi][nd][r] * inv);
    }
}

// ---------------------------------------------------------------------------
// Build bucket matrix T (bf16, row stride 160): T[0]=tail0, T[1..127]=band p,
// T[128]=tail128. One wave per row.
// ---------------------------------------------------------------------------
__global__ __launch_bounds__(256) void build_T_k(
    const unsigned short* __restrict__ pdiag, const float* __restrict__ m_used,
    const float* __restrict__ mstat, const float* __restrict__ lstat,
    const float* __restrict__ t0stat, unsigned short* __restrict__ T) {
  const int w = threadIdx.x >> 6, l = threadIdx.x & 63;
  const int row = blockIdx.x * 4 + w;
  const int q = (row >> 4) & (L_ - 1);
  const float m = mstat[row];
  const float inv = 1.f / lstat[row];
  const float t0 = t0stat[row] * inv;
  float psum = 0.f;
#pragma unroll
  for (int jj = 0; jj < 2; ++jj) {
    int j = l + jj * 64;
    float pf = 0.f;
    if (j < 127) {
      int k = q + j - 63;
      if (k >= 0 && k < L_) {
        float mu = m_used[(size_t)row * 16 + (k >> 6)];
        pf = bf2f(pdiag[(size_t)row * PD_LD + j]) *
             __builtin_amdgcn_exp2f((mu - m) * 1.44269504f) * inv;
      }
      T[(size_t)row * T_LD + 1 + j] = f2bf(pf);
    }
    psum += pf;
  }
#pragma unroll
  for (int off = 1; off < 64; off <<= 1) psum += __shfl_xor(psum, off);
  if (l == 0) {
    T[(size_t)row * T_LD] = f2bf(t0);
    T[(size_t)row * T_LD + 128] = f2bf(fmaxf(0.f, 1.f - t0 - psum));
  }
}

// ---------------------------------------------------------------------------
extern "C" void kernel_launch(void* const* d_in, const int* in_sizes, int n_in,
                              void* d_out, int out_size, void* d_ws, size_t ws_size,
                              hipStream_t stream) {
  (void)in_sizes; (void)n_in; (void)out_size;
  const float* q  = (const float*)d_in[0];
  const float* k  = (const float*)d_in[1];
  const float* v  = (const float*)d_in[2];
  const float* Wq = (const float*)d_in[3];
  const float* bq = (const float*)d_in[4];
  const float* Wk = (const float*)d_in[5];
  const float* bk = (const float*)d_in[6];
  const float* Wv = (const float*)d_in[7];
  const float* bv = (const float*)d_in[8];
  const float* Wo = (const float*)d_in[9];
  const float* bo = (const float*)d_in[10];
  const float* Ek = (const float*)d_in[11];
  const float* Ev = (const float*)d_in[12];

  char* ws = (char*)d_ws;
  constexpr size_t SZ_QKV = (size_t)B_ * L_ * D_ * 2;       // 8 MB
  constexpr size_t SZ_W   = (size_t)D_ * D_ * 2;            // 2 MB
  constexpr size_t OFF_QB = 0;
  constexpr size_t OFF_KB = OFF_QB + SZ_QKV;
  constexpr size_t OFF_VB = OFF_KB + SZ_QKV;
  constexpr size_t OFF_WQ = OFF_VB + SZ_QKV;
  constexpr size_t OFF_WK = OFF_WQ + SZ_W;
  constexpr size_t OFF_WV = OFF_WK + SZ_W;
  constexpr size_t OFF_QE = OFF_WV + SZ_W;                  // NROW*132*2
  constexpr size_t OFF_WO = OFF_QE + (size_t)NROW * QE_LD * 2;
  constexpr size_t OFF_EKP = OFF_WO + SZ_W;                 // 256*64*2
  constexpr size_t OFF_EVT = OFF_EKP + 256 * 64 * 2;        // 128*160*2
  constexpr size_t OFF_QP = OFF_EVT + 128 * 160 * 2;
  constexpr size_t OFF_KP = OFF_QP + SZ_QKV;
  constexpr size_t OFF_VP = OFF_KP + SZ_QKV;
  constexpr size_t OFF_VPT = OFF_VP + SZ_QKV;
  constexpr size_t OFF_MU = OFF_VPT + SZ_QKV;               // NROW*16*4
  constexpr size_t OFF_MS = OFF_MU + (size_t)NROW * 16 * 4;
  constexpr size_t OFF_LS = OFF_MS + (size_t)NROW * 4;
  constexpr size_t OFF_T0 = OFF_LS + (size_t)NROW * 4;
  constexpr size_t OFF_TMP = OFF_T0 + (size_t)NROW * 4;     // NROW*64*2
  // aliased (lifetime-disjoint) regions:
  constexpr size_t OFF_PD = 0;                              // over qb+kb (16 MB)
  constexpr size_t OFF_TB = OFF_VB;                         // over vb..qE prefix (20 MB)
  (void)ws_size;

  auto U16 = [&](size_t off) { return (unsigned short*)(ws + off); };
  auto F32 = [&](size_t off) { return (float*)(ws + off); };

  // converts
  f32_to_bf16_k<<<2048, 256, 0, stream>>>(q, U16(OFF_QB), (B_ * L_ * D_) / 4);
  f32_to_bf16_k<<<2048, 256, 0, stream>>>(k, U16(OFF_KB), (B_ * L_ * D_) / 4);
  f32_to_bf16_k<<<2048, 256, 0, stream>>>(v, U16(OFF_VB), (B_ * L_ * D_) / 4);
  f32_to_bf16_k<<<1024, 256, 0, stream>>>(Wq, U16(OFF_WQ), (D_ * D_) / 4);
  f32_to_bf16_k<<<1024, 256, 0, stream>>>(Wk, U16(OFF_WK), (D_ * D_) / 4);
  f32_to_bf16_k<<<1024, 256, 0, stream>>>(Wv, U16(OFF_WV), (D_ * D_) / 4);
  f32_to_bf16_k<<<1024, 256, 0, stream>>>(Wo, U16(OFF_WO), (D_ * D_) / 4);
  build_ekev_k<<<80, 256, 0, stream>>>(Ek, Ev, U16(OFF_EKP), U16(OFF_EVT));

  // projections: qp/kp/vp = X @ W^T + b   (M=4096,N=1024,K=1024)
  gemm_bt<true, true, false><<<dim3(32, 8), 256, 0, stream>>>(
      U16(OFF_QB), U16(OFF_WQ), bq, U16(OFF_QP), 1024, 1024, 1024, 1024, 32);
  gemm_bt<true, true, false><<<dim3(32, 8), 256, 0, stream>>>(
      U16(OFF_KB), U16(OFF_WK), bk, U16(OFF_KP), 1024, 1024, 1024, 1024, 32);
  gemm_bt<true, true, false><<<dim3(32, 8), 256, 0, stream>>>(
      U16(OFF_VB), U16(OFF_WV), bv, U16(OFF_VP), 1024, 1024, 1024, 1024, 32);

  transpose_v_k<<<dim3(16, 64), 256, 0, stream>>>(U16(OFF_VP), U16(OFF_VPT));

  // qE = qp @ Ek^T  (M=65536,N=256(cut 129),K=64), bf16 out, ldc=132
  gemm_bt<true, false, false><<<dim3(512, 2), 256, 0, stream>>>(
      U16(OFF_QP), U16(OFF_EKP), nullptr, U16(OFF_QE), 64, 64, QE_LD, 129, 2);

  // fused attention
  flash_fwd_k<<<dim3(8, 64), 256, 0, stream>>>(
      U16(OFF_QP), U16(OFF_KP), U16(OFF_VPT), U16(OFF_QE),
      U16(OFF_PD), F32(OFF_MU), F32(OFF_MS), F32(OFF_LS), F32(OFF_T0), U16(OFF_TMP));

  // bucket matrix + out2 accumulate: tmp += T @ Ev
  build_T_k<<<16384, 256, 0, stream>>>(
      U16(OFF_PD), F32(OFF_MU), F32(OFF_MS), F32(OFF_LS), F32(OFF_T0), U16(OFF_TB));
  gemm_bt<true, false, true><<<dim3(512, 1), 256, 0, stream>>>(
      U16(OFF_TB), U16(OFF_EVT), nullptr, U16(OFF_TMP), T_LD, T_LD, 64, 64, 5);

  // out = tmp @ Wo^T + bo  (f32 out)
  gemm_bt<false, true, false><<<dim3(32, 8), 256, 0, stream>>>(
      U16(OFF_TMP), U16(OFF_WO), bo, (float*)d_out, 1024, 1024, 1024, 1024, 32);
}

// Round 2
// 286.977 us; speedup vs baseline: 1.4792x; 1.4792x over previous
//
#include <hip/hip_runtime.h>
#include <stdint.h>
#include <stddef.h>

#define B_ 4
#define L_ 1024
#define D_ 1024
#define H_ 16
#define HD_ 64
#define NROW 65536      // B*L*H
#define QE_LD 132       // qE row stride (bf16 elems)
#define PD_LD 128       // pdiag row stride
#define T_LD 160        // T row stride (= GEMM K, 5 k-tiles of 32)

typedef __attribute__((ext_vector_type(8))) short bf16x8;
typedef __attribute__((ext_vector_type(4))) float f32x4;
typedef __attribute__((ext_vector_type(4))) unsigned short u16x4;

__device__ __forceinline__ float bf2f(unsigned short u) {
  union { unsigned int i; float f; } v; v.i = ((unsigned int)u) << 16; return v.f;
}
__device__ __forceinline__ unsigned short f2bf(float f) {
  union { float f; unsigned int i; } v; v.f = f;
  return (unsigned short)((v.i + 0x7fffu + ((v.i >> 16) & 1u)) >> 16);
}
__device__ __forceinline__ void async16(const void* g, void* l) {
  __builtin_amdgcn_global_load_lds(
      (const __attribute__((address_space(1))) unsigned int*)g,
      (__attribute__((address_space(3))) unsigned int*)l, 16, 0, 0);
}

// ---------------------------------------------------------------------------
// f32 -> bf16 convert, multi-tensor (vectorized x4)
// ---------------------------------------------------------------------------
struct ConvArgs { const float* s[4]; unsigned short* d[4]; };

__global__ __launch_bounds__(256) void f32_to_bf16_multi(ConvArgs a, int n4) {
  const float* s = a.s[blockIdx.y];
  unsigned short* d = a.d[blockIdx.y];
  int i = blockIdx.x * 256 + threadIdx.x;
  int stride = gridDim.x * 256;
  for (; i < n4; i += stride) {
    float4 v = ((const float4*)s)[i];
    u16x4 o;
    o[0] = f2bf(v.x); o[1] = f2bf(v.y); o[2] = f2bf(v.z); o[3] = f2bf(v.w);
    ((u16x4*)d)[i] = o;
  }
}

// Build padded Ek (256x64 bf16, rows>=129 zero) and Ev^T padded (128x160 bf16)
__global__ __launch_bounds__(256) void build_ekev_k(const float* __restrict__ Ek,
                                                    const float* __restrict__ Ev,
                                                    unsigned short* __restrict__ Ekp,
                                                    unsigned short* __restrict__ EvTp) {
  int i = blockIdx.x * 256 + threadIdx.x;
  if (i < 256 * 64) {
    int r = i >> 6, dd = i & 63;
    Ekp[i] = (r < 129) ? f2bf(Ek[r * 64 + dd]) : (unsigned short)0;
  }
  if (i < 128 * 160) {
    int dd = i / 160, r = i - dd * 160;
    EvTp[i] = (dd < 64 && r < 129) ? f2bf(Ev[r * 64 + dd]) : (unsigned short)0;
  }
}

// ---------------------------------------------------------------------------
// GEMM: C[M,N] = A[M,K] * Bt[N,K]^T (+bias) ; bf16 in, f32 acc.
// 128x128 tile, BK=32, 4 waves, chunk-swizzled LDS, global_load_lds x16.
// ---------------------------------------------------------------------------
template<bool OBF16, bool BIAS, bool ACCUM>
__global__ __launch_bounds__(256) void gemm_bt(const unsigned short* __restrict__ A,
                                               const unsigned short* __restrict__ Bt,
                                               const float* __restrict__ bias,
                                               void* __restrict__ Cv,
                                               int lda, int ldb, int ldc, int Ncut, int ktiles) {
  __shared__ unsigned short Al[2][128 * 32];
  __shared__ unsigned short Bl[2][128 * 32];
  const int tid = threadIdx.x;
  const int w = tid >> 6, l = tid & 63;
  const int l15 = l & 15, lg = l >> 4;
  const int row0 = blockIdx.x * 128, col0 = blockIdx.y * 128;
  const int wm = (w >> 1) * 64, wn = (w & 1) * 64;

  f32x4 acc[4][4];
#pragma unroll
  for (int i = 0; i < 4; ++i)
#pragma unroll
    for (int j = 0; j < 4; ++j) acc[i][j] = {0.f, 0.f, 0.f, 0.f};

  auto stage = [&](int buf, int kt) {
#pragma unroll
    for (int i = 0; i < 2; ++i) {
      int p = (i * 4 + w) * 1024 + l * 16;   // byte offset within 8KB tile
      int m = p >> 6;                        // tile-local row (64B rows)
      int clog = (l & 3) ^ ((m >> 1) & 3);   // logical k-chunk for this slot
      async16(A + (size_t)(row0 + m) * lda + kt * 32 + clog * 8,
              (char*)&Al[buf][0] + (i * 4 + w) * 1024);
      async16(Bt + (size_t)(col0 + m) * ldb + kt * 32 + clog * 8,
              (char*)&Bl[buf][0] + (i * 4 + w) * 1024);
    }
  };

  stage(0, 0);
  __syncthreads();
  for (int kt = 0; kt < ktiles; ++kt) {
    int cur = kt & 1;
    if (kt + 1 < ktiles) stage(cur ^ 1, kt + 1);
    bf16x8 af[4], bfr[4];
#pragma unroll
    for (int mi = 0; mi < 4; ++mi) {
      int m = wm + mi * 16 + l15;
      af[mi] = *(const bf16x8*)&Al[cur][m * 32 + ((lg ^ ((m >> 1) & 3)) << 3)];
    }
#pragma unroll
    for (int ni = 0; ni < 4; ++ni) {
      int n = wn + ni * 16 + l15;
      bfr[ni] = *(const bf16x8*)&Bl[cur][n * 32 + ((lg ^ ((n >> 1) & 3)) << 3)];
    }
#pragma unroll
    for (int mi = 0; mi < 4; ++mi)
#pragma unroll
      for (int ni = 0; ni < 4; ++ni)
        acc[mi][ni] = __builtin_amdgcn_mfma_f32_16x16x32_bf16(af[mi], bfr[ni], acc[mi][ni], 0, 0, 0);
    __syncthreads();
  }

#pragma unroll
  for (int ni = 0; ni < 4; ++ni) {
    int col = col0 + wn + ni * 16 + l15;
    if (col < Ncut) {
      float bv = BIAS ? bias[col] : 0.f;
#pragma unroll
      for (int mi = 0; mi < 4; ++mi) {
        int rowb = row0 + wm + mi * 16 + lg * 4;
#pragma unroll
        for (int r = 0; r < 4; ++r) {
          float v = acc[mi][ni][r] + bv;
          size_t off = (size_t)(rowb + r) * ldc + col;
          if (ACCUM) v += bf2f(((const unsigned short*)Cv)[off]);
          if (OBF16) ((unsigned short*)Cv)[off] = f2bf(v);
          else       ((float*)Cv)[off] = v;
        }
      }
    }
  }
}

// ---------------------------------------------------------------------------
// Transpose vp (B,L,H,HD) -> vpT (B,H,HD,L), bf16
// ---------------------------------------------------------------------------
__global__ __launch_bounds__(256) void transpose_v_k(const unsigned short* __restrict__ vp,
                                                     unsigned short* __restrict__ vpT) {
  const int lt = blockIdx.x, bh = blockIdx.y;
  const int b = bh >> 4, h = bh & 15;
  __shared__ unsigned short tile[64][72];
  const int t = threadIdx.x;
#pragma unroll
  for (int j = 0; j < 2; ++j) {
    int lrow = (t >> 3) + 32 * j;
    int d0 = (t & 7) * 8;
    bf16x8 v = *(const bf16x8*)(vp + ((size_t)((b * L_ + lt * 64 + lrow) * H_ + h)) * HD_ + d0);
#pragma unroll
    for (int e = 0; e < 8; ++e) tile[lrow][d0 + e] = (unsigned short)v[e];
  }
  __syncthreads();
#pragma unroll
  for (int j = 0; j < 2; ++j) {
    int d = (t >> 3) + 32 * j;
    int l0 = (t & 7) * 8;
    bf16x8 o;
#pragma unroll
    for (int e = 0; e < 8; ++e) o[e] = (short)tile[l0 + e][d];
    *(bf16x8*)(vpT + ((size_t)((b * H_ + h) * HD_ + d)) * L_ + lt * 64 + l0) = o;
  }
}

// ---------------------------------------------------------------------------
// Fused flash attention with relative-position logits.
// Grid (16 qtiles, 64 bh), 256 thr = 4 waves, Q-tile 64 (16 rows/wave), KV 64.
// Tile classification: LOW (kt <= qt-2, rel logit = qE[0] const/row),
// BAND (qt-1..qt+2, full gather path), HIGH (kt >= qt+3, qE[128] const/row).
// ---------------------------------------------------------------------------
__global__ __launch_bounds__(256, 3) void flash_fwd_k(
    const unsigned short* __restrict__ qp, const unsigned short* __restrict__ kp,
    const unsigned short* __restrict__ vpT, const unsigned short* __restrict__ qE,
    unsigned short* __restrict__ pdiag, float* __restrict__ m_used,
    float* __restrict__ mstat, float* __restrict__ lstat, float* __restrict__ t0stat,
    unsigned short* __restrict__ tmp) {
  __shared__ unsigned short Kl[2][64 * 64];
  __shared__ unsigned short Vl[2][64 * 64];
  __shared__ unsigned short Pl[4][16 * 64];
  const int tid = threadIdx.x, w = tid >> 6, l = tid & 63;
  const int l15 = l & 15, lg = l >> 4;
  const int qt = blockIdx.x, bh = blockIdx.y;
  const int b = bh >> 4, h = bh & 15;
  const int qw = qt * 64 + w * 16;        // wave's first q row
  const int rowbase = (b * L_ + qw) * H_ + h;
  const float L2E = 1.44269504f;

  // Q fragments: row = qw + l15, d-chunk = ks*32 + lg*8
  bf16x8 qf[2];
  {
    const unsigned short* qrp = qp + ((size_t)(rowbase + l15 * H_)) * HD_;
#pragma unroll
    for (int ks = 0; ks < 2; ++ks) qf[ks] = *(const bf16x8*)(qrp + ks * 32 + lg * 8);
  }
  float qe0s[4], qe128s[4];
#pragma unroll
  for (int r = 0; r < 4; ++r) {
    const unsigned short* qe = qE + (size_t)(rowbase + (lg * 4 + r) * H_) * QE_LD;
    qe0s[r] = bf2f(qe[0]) * 0.125f;
    qe128s[r] = bf2f(qe[128]) * 0.125f;
  }

  f32x4 O[4];
#pragma unroll
  for (int nd = 0; nd < 4; ++nd) O[nd] = {0.f, 0.f, 0.f, 0.f};
  float mrow[4], lrow[4], t0row[4];
#pragma unroll
  for (int r = 0; r < 4; ++r) { mrow[r] = -1e30f; lrow[r] = 0.f; t0row[r] = 0.f; }

  auto stage = [&](int buf, int kt) {
#pragma unroll
    for (int i = 0; i < 2; ++i) {
      int p = (i * 4 + w) * 1024 + l * 16;  // byte in 8KB tile (rows = 128B)
      int row = p >> 7;
      int clog = (l & 7) ^ (row & 7);
      async16(kp + ((size_t)((b * L_ + kt * 64 + row) * H_ + h)) * HD_ + clog * 8,
              (char*)&Kl[buf][0] + (i * 4 + w) * 1024);
      async16(vpT + ((size_t)((b * H_ + h) * HD_ + row)) * L_ + kt * 64 + clog * 8,
              (char*)&Vl[buf][0] + (i * 4 + w) * 1024);
    }
  };

  stage(0, 0);
  __syncthreads();

  for (int kt = 0; kt < 16; ++kt) {
    int cur = kt & 1;
    if (kt + 1 < 16) stage(cur ^ 1, kt + 1);

    // S = Q * K^T  (lane: col kk=ni*16+l15, rows q = qw+lg*4+r)
    f32x4 S[4];
#pragma unroll
    for (int ni = 0; ni < 4; ++ni) S[ni] = {0.f, 0.f, 0.f, 0.f};
#pragma unroll
    for (int ks = 0; ks < 2; ++ks) {
      bf16x8 kf[4];
#pragma unroll
      for (int ni = 0; ni < 4; ++ni) {
        int kk = ni * 16 + l15;
        kf[ni] = *(const bf16x8*)&Kl[cur][kk * 64 + (((ks * 4 + lg) ^ (kk & 7)) << 3)];
      }
#pragma unroll
      for (int ni = 0; ni < 4; ++ni)
        S[ni] = __builtin_amdgcn_mfma_f32_16x16x32_bf16(qf[ks], kf[ni], S[ni], 0, 0, 0);
    }

    // classification (block-uniform)
    const int cls = (kt <= qt - 2) ? 0 : ((kt >= qt + 3) ? 2 : 1);

    float alpha[4];
#pragma unroll
    for (int r = 0; r < 4; ++r) {
      float sv[4];
      float ps = 0.f, ps0 = 0.f;
      if (cls == 1) {
        int q = qw + lg * 4 + r;
        const unsigned short* qerow = qE + (size_t)(rowbase + (lg * 4 + r) * H_) * QE_LD;
#pragma unroll
        for (int ni = 0; ni < 4; ++ni) {
          int delta = kt * 64 + ni * 16 + l15 - q;
          float qes;
          if (delta >= 64) qes = qe128s[r];
          else if (delta <= -64) qes = qe0s[r];
          else qes = bf2f(qerow[delta + 64]) * 0.125f;
          sv[ni] = S[ni][r] * 0.125f + qes;
        }
      } else {
        float qes = (cls == 0) ? qe0s[r] : qe128s[r];
#pragma unroll
        for (int ni = 0; ni < 4; ++ni) sv[ni] = S[ni][r] * 0.125f + qes;
      }
      float vmax = fmaxf(fmaxf(sv[0], sv[1]), fmaxf(sv[2], sv[3]));
      vmax = fmaxf(vmax, __shfl_xor(vmax, 1));
      vmax = fmaxf(vmax, __shfl_xor(vmax, 2));
      vmax = fmaxf(vmax, __shfl_xor(vmax, 4));
      vmax = fmaxf(vmax, __shfl_xor(vmax, 8));
      float mold = mrow[r];
      float mnew = fmaxf(mold, vmax);
      alpha[r] = __builtin_amdgcn_exp2f((mold - mnew) * L2E);
      mrow[r] = mnew;
      if (cls == 1) {
        int q = qw + lg * 4 + r;
#pragma unroll
        for (int ni = 0; ni < 4; ++ni) {
          float p = __builtin_amdgcn_exp2f((sv[ni] - mnew) * L2E);
          S[ni][r] = p;
          ps += p;
          int delta = kt * 64 + ni * 16 + l15 - q;
          if (delta <= -64) ps0 += p;
          if (delta > -64 && delta < 64)
            pdiag[(size_t)(rowbase + (lg * 4 + r) * H_) * PD_LD + (delta + 63)] = f2bf(p);
        }
        ps0 += __shfl_xor(ps0, 1); ps0 += __shfl_xor(ps0, 2);
        ps0 += __shfl_xor(ps0, 4); ps0 += __shfl_xor(ps0, 8);
        if (l15 == 0) {
          if (kt * 64 <= q + 63 && kt * 64 + 63 >= q - 63)
            m_used[(size_t)(rowbase + (lg * 4 + r) * H_) * 16 + kt] = mnew;
        }
      } else {
#pragma unroll
        for (int ni = 0; ni < 4; ++ni) {
          float p = __builtin_amdgcn_exp2f((sv[ni] - mnew) * L2E);
          S[ni][r] = p;
          ps += p;
        }
      }
      ps += __shfl_xor(ps, 1); ps += __shfl_xor(ps, 2);
      ps += __shfl_xor(ps, 4); ps += __shfl_xor(ps, 8);
      lrow[r] = lrow[r] * alpha[r] + ps;
      if (cls == 0)      t0row[r] = t0row[r] * alpha[r] + ps;
      else if (cls == 2) t0row[r] = t0row[r] * alpha[r];
      else               t0row[r] = t0row[r] * alpha[r] + ps0;
    }

    // rescale O
#pragma unroll
    for (int nd = 0; nd < 4; ++nd)
#pragma unroll
      for (int r = 0; r < 4; ++r) O[nd][r] *= alpha[r];

    // write P (bf16) to per-wave LDS, chunk-XOR-swizzled rows of 128B
#pragma unroll
    for (int ni = 0; ni < 4; ++ni)
#pragma unroll
      for (int r = 0; r < 4; ++r) {
        int qloc = lg * 4 + r;
        int kk = ni * 16 + l15;
        Pl[w][qloc * 64 + ((((kk >> 3) ^ (qloc & 7)) << 3) | (kk & 7))] = f2bf(S[ni][r]);
      }

    // O += P * V   (same-wave LDS dep: compiler inserts lgkmcnt)
#pragma unroll
    for (int ks = 0; ks < 2; ++ks) {
      bf16x8 pf = *(const bf16x8*)&Pl[w][l15 * 64 + (((ks * 4 + lg) ^ (l15 & 7)) << 3)];
      bf16x8 vf[4];
#pragma unroll
      for (int nd = 0; nd < 4; ++nd) {
        int d = nd * 16 + l15;
        vf[nd] = *(const bf16x8*)&Vl[cur][d * 64 + (((ks * 4 + lg) ^ (d & 7)) << 3)];
      }
#pragma unroll
      for (int nd = 0; nd < 4; ++nd)
        O[nd] = __builtin_amdgcn_mfma_f32_16x16x32_bf16(pf, vf[nd], O[nd], 0, 0, 0);
    }
    __syncthreads();
  }

  // epilogue: normalize + store out1; stats
#pragma unroll
  for (int r = 0; r < 4; ++r) {
    int rowi = rowbase + (lg * 4 + r) * H_;
    float inv = 1.f / lrow[r];
    if (l15 == 0) {
      mstat[rowi] = mrow[r];
      lstat[rowi] = lrow[r];
      t0stat[rowi] = t0row[r];
    }
#pragma unroll
    for (int nd = 0; nd < 4; ++nd)
      tmp[(size_t)rowi * HD_ + nd * 16 + l15] = f2bf(O[nd][r] * inv);
  }
}

// ---------------------------------------------------------------------------
// Build bucket matrix T (bf16, row stride 160): T[0]=tail0, T[1..127]=band p,
// T[128]=tail128. One wave per row.
// ---------------------------------------------------------------------------
__global__ __launch_bounds__(256) void build_T_k(
    const unsigned short* __restrict__ pdiag, const float* __restrict__ m_used,
    const float* __restrict__ mstat, const float* __restrict__ lstat,
    const float* __restrict__ t0stat, unsigned short* __restrict__ T) {
  const int w = threadIdx.x >> 6, l = threadIdx.x & 63;
  const int row = blockIdx.x * 4 + w;
  const int q = (row >> 4) & (L_ - 1);
  const float m = mstat[row];
  const float inv = 1.f / lstat[row];
  const float t0 = t0stat[row] * inv;
  float psum = 0.f;
#pragma unroll
  for (int jj = 0; jj < 2; ++jj) {
    int j = l + jj * 64;
    float pf = 0.f;
    if (j < 127) {
      int k = q + j - 63;
      if (k >= 0 && k < L_) {
        float mu = m_used[(size_t)row * 16 + (k >> 6)];
        pf = bf2f(pdiag[(size_t)row * PD_LD + j]) *
             __builtin_amdgcn_exp2f((mu - m) * 1.44269504f) * inv;
      }
      T[(size_t)row * T_LD + 1 + j] = f2bf(pf);
    }
    psum += pf;
  }
#pragma unroll
  for (int off = 1; off < 64; off <<= 1) psum += __shfl_xor(psum, off);
  if (l == 0) {
    T[(size_t)row * T_LD] = f2bf(t0);
    T[(size_t)row * T_LD + 128] = f2bf(fmaxf(0.f, 1.f - t0 - psum));
  }
}

// ---------------------------------------------------------------------------
extern "C" void kernel_launch(void* const* d_in, const int* in_sizes, int n_in,
                              void* d_out, int out_size, void* d_ws, size_t ws_size,
                              hipStream_t stream) {
  (void)in_sizes; (void)n_in; (void)out_size;
  const float* q  = (const float*)d_in[0];
  const float* k  = (const float*)d_in[1];
  const float* v  = (const float*)d_in[2];
  const float* Wq = (const float*)d_in[3];
  const float* bq = (const float*)d_in[4];
  const float* Wk = (const float*)d_in[5];
  const float* bk = (const float*)d_in[6];
  const float* Wv = (const float*)d_in[7];
  const float* bv = (const float*)d_in[8];
  const float* Wo = (const float*)d_in[9];
  const float* bo = (const float*)d_in[10];
  const float* Ek = (const float*)d_in[11];
  const float* Ev = (const float*)d_in[12];

  char* ws = (char*)d_ws;
  constexpr size_t SZ_QKV = (size_t)B_ * L_ * D_ * 2;       // 8 MB
  constexpr size_t SZ_W   = (size_t)D_ * D_ * 2;            // 2 MB
  constexpr size_t OFF_QB = 0;
  constexpr size_t OFF_KB = OFF_QB + SZ_QKV;
  constexpr size_t OFF_VB = OFF_KB + SZ_QKV;
  constexpr size_t OFF_WQ = OFF_VB + SZ_QKV;
  constexpr size_t OFF_WK = OFF_WQ + SZ_W;
  constexpr size_t OFF_WV = OFF_WK + SZ_W;
  constexpr size_t OFF_QE = OFF_WV + SZ_W;                  // NROW*132*2
  constexpr size_t OFF_WO = OFF_QE + (size_t)NROW * QE_LD * 2;
  constexpr size_t OFF_EKP = OFF_WO + SZ_W;                 // 256*64*2
  constexpr size_t OFF_EVT = OFF_EKP + 256 * 64 * 2;        // 128*160*2
  constexpr size_t OFF_QP = OFF_EVT + 128 * 160 * 2;
  constexpr size_t OFF_KP = OFF_QP + SZ_QKV;
  constexpr size_t OFF_VP = OFF_KP + SZ_QKV;
  constexpr size_t OFF_VPT = OFF_VP + SZ_QKV;
  constexpr size_t OFF_MU = OFF_VPT + SZ_QKV;               // NROW*16*4
  constexpr size_t OFF_MS = OFF_MU + (size_t)NROW * 16 * 4;
  constexpr size_t OFF_LS = OFF_MS + (size_t)NROW * 4;
  constexpr size_t OFF_T0 = OFF_LS + (size_t)NROW * 4;
  constexpr size_t OFF_TMP = OFF_T0 + (size_t)NROW * 4;     // NROW*64*2
  // aliased (lifetime-disjoint) regions:
  constexpr size_t OFF_PD = 0;                              // over qb+kb (16 MB)
  constexpr size_t OFF_TB = OFF_VB;                         // over vb..qE prefix (20 MB)
  (void)ws_size;

  auto U16 = [&](size_t off) { return (unsigned short*)(ws + off); };
  auto F32 = [&](size_t off) { return (float*)(ws + off); };

  // converts (merged launches)
  {
    ConvArgs a{};
    a.s[0] = q; a.s[1] = k; a.s[2] = v;
    a.d[0] = U16(OFF_QB); a.d[1] = U16(OFF_KB); a.d[2] = U16(OFF_VB);
    f32_to_bf16_multi<<<dim3(2048, 3), 256, 0, stream>>>(a, (B_ * L_ * D_) / 4);
    ConvArgs b{};
    b.s[0] = Wq; b.s[1] = Wk; b.s[2] = Wv; b.s[3] = Wo;
    b.d[0] = U16(OFF_WQ); b.d[1] = U16(OFF_WK); b.d[2] = U16(OFF_WV); b.d[3] = U16(OFF_WO);
    f32_to_bf16_multi<<<dim3(1024, 4), 256, 0, stream>>>(b, (D_ * D_) / 4);
  }
  build_ekev_k<<<80, 256, 0, stream>>>(Ek, Ev, U16(OFF_EKP), U16(OFF_EVT));

  // projections: qp/kp/vp = X @ W^T + b   (M=4096,N=1024,K=1024)
  gemm_bt<true, true, false><<<dim3(32, 8), 256, 0, stream>>>(
      U16(OFF_QB), U16(OFF_WQ), bq, U16(OFF_QP), 1024, 1024, 1024, 1024, 32);
  gemm_bt<true, true, false><<<dim3(32, 8), 256, 0, stream>>>(
      U16(OFF_KB), U16(OFF_WK), bk, U16(OFF_KP), 1024, 1024, 1024, 1024, 32);
  gemm_bt<true, true, false><<<dim3(32, 8), 256, 0, stream>>>(
      U16(OFF_VB), U16(OFF_WV), bv, U16(OFF_VP), 1024, 1024, 1024, 1024, 32);

  transpose_v_k<<<dim3(16, 64), 256, 0, stream>>>(U16(OFF_VP), U16(OFF_VPT));

  // qE = qp @ Ek^T  (M=65536,N=256(cut 129),K=64), bf16 out, ldc=132
  gemm_bt<true, false, false><<<dim3(512, 2), 256, 0, stream>>>(
      U16(OFF_QP), U16(OFF_EKP), nullptr, U16(OFF_QE), 64, 64, QE_LD, 129, 2);

  // fused attention
  flash_fwd_k<<<dim3(16, 64), 256, 0, stream>>>(
      U16(OFF_QP), U16(OFF_KP), U16(OFF_VPT), U16(OFF_QE),
      U16(OFF_PD), F32(OFF_MU), F32(OFF_MS), F32(OFF_LS), F32(OFF_T0), U16(OFF_TMP));

  // bucket matrix + out2 accumulate: tmp += T @ Ev
  build_T_k<<<16384, 256, 0, stream>>>(
      U16(OFF_PD), F32(OFF_MU), F32(OFF_MS), F32(OFF_LS), F32(OFF_T0), U16(OFF_TB));
  gemm_bt<true, false, true><<<dim3(512, 1), 256, 0, stream>>>(
      U16(OFF_TB), U16(OFF_EVT), nullptr, U16(OFF_TMP), T_LD, T_LD, 64, 64, 5);

  // out = tmp @ Wo^T + bo  (f32 out)
  gemm_bt<false, true, false><<<dim3(32, 8), 256, 0, stream>>>(
      U16(OFF_TMP), U16(OFF_WO), bo, (float*)d_out, 1024, 1024, 1024, 1024, 32);
}

// Round 3
// 218.070 us; speedup vs baseline: 1.9466x; 1.3160x over previous
//
#include <hip/hip_runtime.h>
#include <hip/hip_bf16.h>
#include <stdint.h>
#include <stddef.h>

#define B_ 4
#define L_ 1024
#define D_ 1024
#define H_ 16
#define HD_ 64
#define NROW 65536      // B*L*H
#define QE_LD 132       // qE row stride (bf16 elems)
#define PB_LD 192       // pband / T row stride (= out2 GEMM K, 6 k-tiles of 32)

typedef __attribute__((ext_vector_type(8))) short bf16x8;
typedef __attribute__((ext_vector_type(4))) float f32x4;
typedef __attribute__((ext_vector_type(4))) unsigned short u16x4;

__device__ __forceinline__ float bf2f(unsigned short u) {
  union { unsigned int i; float f; } v; v.i = ((unsigned int)u) << 16; return v.f;
}
__device__ __forceinline__ unsigned short f2bf(float f) {
  union { float f; unsigned int i; } v; v.f = f;
  return (unsigned short)((v.i + 0x7fffu + ((v.i >> 16) & 1u)) >> 16);
}
__device__ __forceinline__ unsigned short f2bfrn(float f) {
  __hip_bfloat16 h = __float2bfloat16(f);
  return *reinterpret_cast<unsigned short*>(&h);
}
__device__ __forceinline__ void async16(const void* g, void* l) {
  __builtin_amdgcn_global_load_lds(
      (const __attribute__((address_space(1))) unsigned int*)g,
      (__attribute__((address_space(3))) unsigned int*)l, 16, 0, 0);
}

// ---------------------------------------------------------------------------
// f32 -> bf16 convert, multi-tensor (vectorized x4)
// ---------------------------------------------------------------------------
struct ConvArgs { const float* s[4]; unsigned short* d[4]; };

__global__ __launch_bounds__(256) void f32_to_bf16_multi(ConvArgs a, int n4) {
  const float* s = a.s[blockIdx.y];
  unsigned short* d = a.d[blockIdx.y];
  int i = blockIdx.x * 256 + threadIdx.x;
  int stride = gridDim.x * 256;
  for (; i < n4; i += stride) {
    float4 v = ((const float4*)s)[i];
    u16x4 o;
    o[0] = f2bf(v.x); o[1] = f2bf(v.y); o[2] = f2bf(v.z); o[3] = f2bf(v.w);
    ((u16x4*)d)[i] = o;
  }
}

// Build padded Ek (256x64 bf16, rows>=129 zero) and Ev^T padded (128x192 bf16,
// cols >=129 zero so pband garbage columns multiply to 0)
__global__ __launch_bounds__(256) void build_ekev_k(const float* __restrict__ Ek,
                                                    const float* __restrict__ Ev,
                                                    unsigned short* __restrict__ Ekp,
                                                    unsigned short* __restrict__ EvTp) {
  int i = blockIdx.x * 256 + threadIdx.x;
  if (i < 256 * 64) {
    int r = i >> 6, dd = i & 63;
    Ekp[i] = (r < 129) ? f2bf(Ek[r * 64 + dd]) : (unsigned short)0;
  }
  if (i < 128 * PB_LD) {
    int dd = i / PB_LD, r = i - dd * PB_LD;
    EvTp[i] = (dd < 64 && r < 129) ? f2bf(Ev[r * 64 + dd]) : (unsigned short)0;
  }
}

// ---------------------------------------------------------------------------
// GEMM: C[M,N] = A[M,K] * Bt[N,K]^T (+bias) ; bf16 in, f32 acc.
// 128x128 tile, BK=32, 4 waves, chunk-swizzled LDS, global_load_lds x16.
// ---------------------------------------------------------------------------
template<bool OBF16, bool BIAS, bool ACCUM>
__global__ __launch_bounds__(256) void gemm_bt(const unsigned short* __restrict__ A,
                                               const unsigned short* __restrict__ Bt,
                                               const float* __restrict__ bias,
                                               void* __restrict__ Cv,
                                               int lda, int ldb, int ldc, int Ncut, int ktiles) {
  __shared__ unsigned short Al[2][128 * 32];
  __shared__ unsigned short Bl[2][128 * 32];
  const int tid = threadIdx.x;
  const int w = tid >> 6, l = tid & 63;
  const int l15 = l & 15, lg = l >> 4;
  const int row0 = blockIdx.x * 128, col0 = blockIdx.y * 128;
  const int wm = (w >> 1) * 64, wn = (w & 1) * 64;

  f32x4 acc[4][4];
#pragma unroll
  for (int i = 0; i < 4; ++i)
#pragma unroll
    for (int j = 0; j < 4; ++j) acc[i][j] = {0.f, 0.f, 0.f, 0.f};

  auto stage = [&](int buf, int kt) {
#pragma unroll
    for (int i = 0; i < 2; ++i) {
      int p = (i * 4 + w) * 1024 + l * 16;   // byte offset within 8KB tile
      int m = p >> 6;                        // tile-local row (64B rows)
      int clog = (l & 3) ^ ((m >> 1) & 3);   // logical k-chunk for this slot
      async16(A + (size_t)(row0 + m) * lda + kt * 32 + clog * 8,
              (char*)&Al[buf][0] + (i * 4 + w) * 1024);
      async16(Bt + (size_t)(col0 + m) * ldb + kt * 32 + clog * 8,
              (char*)&Bl[buf][0] + (i * 4 + w) * 1024);
    }
  };

  stage(0, 0);
  __syncthreads();
  for (int kt = 0; kt < ktiles; ++kt) {
    int cur = kt & 1;
    if (kt + 1 < ktiles) stage(cur ^ 1, kt + 1);
    bf16x8 af[4], bfr[4];
#pragma unroll
    for (int mi = 0; mi < 4; ++mi) {
      int m = wm + mi * 16 + l15;
      af[mi] = *(const bf16x8*)&Al[cur][m * 32 + ((lg ^ ((m >> 1) & 3)) << 3)];
    }
#pragma unroll
    for (int ni = 0; ni < 4; ++ni) {
      int n = wn + ni * 16 + l15;
      bfr[ni] = *(const bf16x8*)&Bl[cur][n * 32 + ((lg ^ ((n >> 1) & 3)) << 3)];
    }
#pragma unroll
    for (int mi = 0; mi < 4; ++mi)
#pragma unroll
      for (int ni = 0; ni < 4; ++ni)
        acc[mi][ni] = __builtin_amdgcn_mfma_f32_16x16x32_bf16(af[mi], bfr[ni], acc[mi][ni], 0, 0, 0);
    __syncthreads();
  }

#pragma unroll
  for (int ni = 0; ni < 4; ++ni) {
    int col = col0 + wn + ni * 16 + l15;
    if (col < Ncut) {
      float bv = BIAS ? bias[col] : 0.f;
#pragma unroll
      for (int mi = 0; mi < 4; ++mi) {
        int rowb = row0 + wm + mi * 16 + lg * 4;
#pragma unroll
        for (int r = 0; r < 4; ++r) {
          float v = acc[mi][ni][r] + bv;
          size_t off = (size_t)(rowb + r) * ldc + col;
          if (ACCUM) v += bf2f(((const unsigned short*)Cv)[off]);
          if (OBF16) ((unsigned short*)Cv)[off] = f2bf(v);
          else       ((float*)Cv)[off] = v;
        }
      }
    }
  }
}

// ---------------------------------------------------------------------------
// Transpose vp (B,L,H,HD) -> vpT (B,H,HD,L), bf16
// ---------------------------------------------------------------------------
__global__ __launch_bounds__(256) void transpose_v_k(const unsigned short* __restrict__ vp,
                                                     unsigned short* __restrict__ vpT) {
  const int lt = blockIdx.x, bh = blockIdx.y;
  const int b = bh >> 4, h = bh & 15;
  __shared__ unsigned short tile[64][72];
  const int t = threadIdx.x;
#pragma unroll
  for (int j = 0; j < 2; ++j) {
    int lrow = (t >> 3) + 32 * j;
    int d0 = (t & 7) * 8;
    bf16x8 v = *(const bf16x8*)(vp + ((size_t)((b * L_ + lt * 64 + lrow) * H_ + h)) * HD_ + d0);
#pragma unroll
    for (int e = 0; e < 8; ++e) tile[lrow][d0 + e] = (unsigned short)v[e];
  }
  __syncthreads();
#pragma unroll
  for (int j = 0; j < 2; ++j) {
    int d = (t >> 3) + 32 * j;
    int l0 = (t & 7) * 8;
    bf16x8 o;
#pragma unroll
    for (int e = 0; e < 8; ++e) o[e] = (short)tile[l0 + e][d];
    *(bf16x8*)(vpT + ((size_t)((b * H_ + h) * HD_ + d)) * L_ + lt * 64 + l0) = o;
  }
}

// ---------------------------------------------------------------------------
// Fused flash attention with relative-position logits.  SWAPPED QK^T:
// S^T = mfma(K, Q) so each lane owns one q-row (q = qw + l15): row reductions
// are 2 shuffles (xor16/xor32).  Log2-domain softmax, defer-max THR=8.
// Grid: 1024 linear blocks, bh = bid&63 (same bh -> same XCD), qt = bid>>6.
// 4 waves, Q-tile 64 (16 rows/wave), KV-tile 64.
// Band tiles: kt in {qt-1, qt, qt+1} (bt = kt-qt+1 in [0,3)).
// pband[row][bt*64 + klocal] = raw p (unconditional, aligned b64 packs);
// m_used[row][bt] = log2-domain max used for that tile.
// ---------------------------------------------------------------------------
__global__ __launch_bounds__(256, 3) void flash_fwd_k(
    const unsigned short* __restrict__ qp, const unsigned short* __restrict__ kp,
    const unsigned short* __restrict__ vpT, const unsigned short* __restrict__ qE,
    unsigned short* __restrict__ pband, float* __restrict__ m_used,
    float* __restrict__ mstat, float* __restrict__ lstat, float* __restrict__ t0stat,
    unsigned short* __restrict__ tmp) {
  __shared__ unsigned short Kl[2][64 * 64];
  __shared__ unsigned short Vl[2][64 * 64];
  __shared__ unsigned short Pl[4][16 * 64];
  const int tid = threadIdx.x, w = tid >> 6, l = tid & 63;
  const int l15 = l & 15, lg = l >> 4;
  const int bid = blockIdx.x;
  const int bh = bid & 63, qt = bid >> 6;
  const int b = bh >> 4, h = bh & 15;
  const int qw = qt * 64 + w * 16;
  const int q_lane = qw + l15;                 // this lane's q row
  const int rowbase = (b * L_ + qw) * H_ + h;
  const int rowi_lane = rowbase + l15 * H_;
  constexpr float C1 = 0.125f * 1.44269504f;   // scale * log2(e)

  // Q fragments (B-operand): col = q = qw + l15, k-chunk = ks*32 + lg*8
  bf16x8 qf[2];
  {
    const unsigned short* qrp = qp + (size_t)rowi_lane * HD_;
#pragma unroll
    for (int ks = 0; ks < 2; ++ks) qf[ks] = *(const bf16x8*)(qrp + ks * 32 + lg * 8);
  }
  const unsigned short* qerow = qE + (size_t)rowi_lane * QE_LD;
  const float qe0L = bf2f(qerow[0]) * C1;
  const float qe128L = bf2f(qerow[128]) * C1;

  f32x4 O[4];
#pragma unroll
  for (int nd = 0; nd < 4; ++nd) O[nd] = {0.f, 0.f, 0.f, 0.f};
  float mrow = -1e30f, lrow = 0.f, t0row = 0.f;   // mrow in log2-units

  auto stage = [&](int buf, int kt) {
#pragma unroll
    for (int i = 0; i < 2; ++i) {
      int p = (i * 4 + w) * 1024 + l * 16;  // byte in 8KB tile (rows = 128B)
      int row = p >> 7;
      int clog = (l & 7) ^ (row & 7);
      async16(kp + ((size_t)((b * L_ + kt * 64 + row) * H_ + h)) * HD_ + clog * 8,
              (char*)&Kl[buf][0] + (i * 4 + w) * 1024);
      async16(vpT + ((size_t)((b * H_ + h) * HD_ + row)) * L_ + kt * 64 + clog * 8,
              (char*)&Vl[buf][0] + (i * 4 + w) * 1024);
    }
  };

  stage(0, 0);
  __syncthreads();

  for (int kt = 0; kt < 16; ++kt) {
    int cur = kt & 1;
    if (kt + 1 < 16) stage(cur ^ 1, kt + 1);

    // S^T = K * Q^T: lane col = q (l15), rows = k-local (ni*16 + lg*4 + r)
    f32x4 S[4];
#pragma unroll
    for (int ni = 0; ni < 4; ++ni) S[ni] = {0.f, 0.f, 0.f, 0.f};
#pragma unroll
    for (int ks = 0; ks < 2; ++ks) {
      bf16x8 kf[4];
#pragma unroll
      for (int ni = 0; ni < 4; ++ni) {
        int kk = ni * 16 + l15;
        kf[ni] = *(const bf16x8*)&Kl[cur][kk * 64 + (((ks * 4 + lg) ^ (kk & 7)) << 3)];
      }
#pragma unroll
      for (int ni = 0; ni < 4; ++ni)
        S[ni] = __builtin_amdgcn_mfma_f32_16x16x32_bf16(kf[ni], qf[ks], S[ni], 0, 0, 0);
    }

    const int cls = (kt <= qt - 2) ? 0 : ((kt >= qt + 2) ? 2 : 1);
    const int bt = kt - qt + 1;
    const int based = kt * 64 - q_lane;

    // logits in log2 domain
    if (cls == 1) {
#pragma unroll
      for (int ni = 0; ni < 4; ++ni)
#pragma unroll
        for (int r = 0; r < 4; ++r) {
          int delta = based + ni * 16 + lg * 4 + r;
          int idx = min(max(delta, -64), 64) + 64;
          S[ni][r] = S[ni][r] * C1 + bf2f(qerow[idx]) * C1;
        }
    } else {
      float qeL = (cls == 0) ? qe0L : qe128L;
#pragma unroll
      for (int ni = 0; ni < 4; ++ni)
#pragma unroll
        for (int r = 0; r < 4; ++r) S[ni][r] = S[ni][r] * C1 + qeL;
    }

    // row max: reg tree + 2 shuffles
    float x0 = fmaxf(fmaxf(S[0][0], S[0][1]), fmaxf(S[0][2], S[0][3]));
    float x1 = fmaxf(fmaxf(S[1][0], S[1][1]), fmaxf(S[1][2], S[1][3]));
    float x2 = fmaxf(fmaxf(S[2][0], S[2][1]), fmaxf(S[2][2], S[2][3]));
    float x3 = fmaxf(fmaxf(S[3][0], S[3][1]), fmaxf(S[3][2], S[3][3]));
    float pmax = fmaxf(fmaxf(x0, x1), fmaxf(x2, x3));
    pmax = fmaxf(pmax, __shfl_xor(pmax, 16));
    pmax = fmaxf(pmax, __shfl_xor(pmax, 32));

    // defer-max (THR = 8 nats = 11.54 log2-units)
    float a = 1.f;
    if (!__all(pmax <= mrow + 11.54f)) {
      float mnew = fmaxf(mrow, pmax);
      a = __builtin_amdgcn_exp2f(mrow - mnew);
      mrow = mnew;
      float aq0 = __shfl(a, lg * 4 + 0);
      float aq1 = __shfl(a, lg * 4 + 1);
      float aq2 = __shfl(a, lg * 4 + 2);
      float aq3 = __shfl(a, lg * 4 + 3);
#pragma unroll
      for (int nd = 0; nd < 4; ++nd) {
        O[nd][0] *= aq0; O[nd][1] *= aq1; O[nd][2] *= aq2; O[nd][3] *= aq3;
      }
    }

    // p = exp2(sL - mL)
#pragma unroll
    for (int ni = 0; ni < 4; ++ni)
#pragma unroll
      for (int r = 0; r < 4; ++r)
        S[ni][r] = __builtin_amdgcn_exp2f(S[ni][r] - mrow);

    float s0 = (S[0][0] + S[0][1]) + (S[0][2] + S[0][3]);
    float s1 = (S[1][0] + S[1][1]) + (S[1][2] + S[1][3]);
    float s2 = (S[2][0] + S[2][1]) + (S[2][2] + S[2][3]);
    float s3 = (S[3][0] + S[3][1]) + (S[3][2] + S[3][3]);
    float ps = (s0 + s1) + (s2 + s3);
    ps += __shfl_xor(ps, 16);
    ps += __shfl_xor(ps, 32);
    lrow = lrow * a + ps;

    if (cls == 0) {
      t0row = t0row * a + ps;
    } else if (cls == 2) {
      t0row = t0row * a;
    } else if (kt == qt - 1) {
      float p0 = 0.f;
#pragma unroll
      for (int ni = 0; ni < 4; ++ni)
#pragma unroll
        for (int r = 0; r < 4; ++r)
          if (based + ni * 16 + lg * 4 + r <= -64) p0 += S[ni][r];
      p0 += __shfl_xor(p0, 16);
      p0 += __shfl_xor(p0, 32);
      t0row = t0row * a + p0;
    } else {
      t0row = t0row * a;
    }

    // pack p to bf16; write Pl (per-wave, swizzled) and pband (band tiles)
    u16x4 pks[4];
#pragma unroll
    for (int ni = 0; ni < 4; ++ni) {
      u16x4 pk;
#pragma unroll
      for (int r = 0; r < 4; ++r) pk[r] = f2bfrn(S[ni][r]);
      pks[ni] = pk;
      int slot = (ni * 2 + (lg >> 1)) ^ (l15 & 7);
      int addr = l15 * 64 + (slot << 3) + (lg & 1) * 4;
      *(u16x4*)&Pl[w][addr] = pk;
    }
    if (cls == 1) {
      unsigned short* pb = pband + (size_t)rowi_lane * PB_LD + bt * 64 + lg * 4;
#pragma unroll
      for (int ni = 0; ni < 4; ++ni) *(u16x4*)(pb + ni * 16) = pks[ni];
      if (lg == 0) m_used[rowi_lane * 4 + bt] = mrow;
    }

    // O += P * V  (Pl same-wave dep; Vl from barrier)
#pragma unroll
    for (int ks = 0; ks < 2; ++ks) {
      bf16x8 pf = *(const bf16x8*)&Pl[w][l15 * 64 + (((ks * 4 + lg) ^ (l15 & 7)) << 3)];
      bf16x8 vf[4];
#pragma unroll
      for (int nd = 0; nd < 4; ++nd) {
        int d = nd * 16 + l15;
        vf[nd] = *(const bf16x8*)&Vl[cur][d * 64 + (((ks * 4 + lg) ^ (d & 7)) << 3)];
      }
#pragma unroll
      for (int nd = 0; nd < 4; ++nd)
        O[nd] = __builtin_amdgcn_mfma_f32_16x16x32_bf16(pf, vf[nd], O[nd], 0, 0, 0);
    }
    __syncthreads();
  }

  // epilogue: stats (per-lane row l15) + normalized out1 (rows lg*4+r)
  float invl = 1.f / lrow;
  if (lg == 0) {
    mstat[rowi_lane] = mrow;
    lstat[rowi_lane] = lrow;
    t0stat[rowi_lane] = t0row;
  }
  float iq[4];
#pragma unroll
  for (int r = 0; r < 4; ++r) iq[r] = __shfl(invl, lg * 4 + r);
#pragma unroll
  for (int r = 0; r < 4; ++r) {
    size_t rowi = (size_t)(rowbase + (lg * 4 + r) * H_);
#pragma unroll
    for (int nd = 0; nd < 4; ++nd)
      tmp[rowi * HD_ + nd * 16 + l15] = f2bfrn(O[nd][r] * iq[r]);
  }
}

// ---------------------------------------------------------------------------
// Build bucket matrix T in-place over pband (stride 192, row-aligned overlay):
// T[0]=tail0, T[1..127]=normalized band p, T[128]=tailH. One wave per row.
// All loads of a row precede its stores (data-dep ordering; disjoint offsets
// across unrolled iterations verified).
// ---------------------------------------------------------------------------
__global__ __launch_bounds__(256) void build_T_k(
    unsigned short* __restrict__ TP, const float* __restrict__ m_used,
    const float* __restrict__ mstat, const float* __restrict__ lstat,
    const float* __restrict__ t0stat) {
  const int w = threadIdx.x >> 6, l = threadIdx.x & 63;
  const int row = blockIdx.x * 4 + w;
  const int q = (row >> 4) & (L_ - 1);
  const float m = mstat[row];
  const float inv = 1.f / lstat[row];
  const float t0 = t0stat[row] * inv;
  float psum = 0.f;
#pragma unroll
  for (int jj = 0; jj < 2; ++jj) {
    int j = l + jj * 64;
    float pf = 0.f;
    if (j < 127) {
      int k = q + j - 63;
      if (k >= 0 && k < L_) {
        int bt = (k >> 6) - (q >> 6) + 1;
        float mu = m_used[row * 4 + bt];
        pf = bf2f(TP[(size_t)row * PB_LD + bt * 64 + (k & 63)]) *
             __builtin_amdgcn_exp2f(mu - m) * inv;
      }
      TP[(size_t)row * PB_LD + 1 + j] = f2bfrn(pf);
    }
    psum += pf;
  }
#pragma unroll
  for (int off = 1; off < 64; off <<= 1) psum += __shfl_xor(psum, off);
  if (l == 0) {
    TP[(size_t)row * PB_LD] = f2bfrn(t0);
    TP[(size_t)row * PB_LD + 128] = f2bfrn(fmaxf(0.f, 1.f - t0 - psum));
  }
}

// ---------------------------------------------------------------------------
extern "C" void kernel_launch(void* const* d_in, const int* in_sizes, int n_in,
                              void* d_out, int out_size, void* d_ws, size_t ws_size,
                              hipStream_t stream) {
  (void)in_sizes; (void)n_in; (void)out_size; (void)ws_size;
  const float* q  = (const float*)d_in[0];
  const float* k  = (const float*)d_in[1];
  const float* v  = (const float*)d_in[2];
  const float* Wq = (const float*)d_in[3];
  const float* bq = (const float*)d_in[4];
  const float* Wk = (const float*)d_in[5];
  const float* bk = (const float*)d_in[6];
  const float* Wv = (const float*)d_in[7];
  const float* bv = (const float*)d_in[8];
  const float* Wo = (const float*)d_in[9];
  const float* bo = (const float*)d_in[10];
  const float* Ek = (const float*)d_in[11];
  const float* Ev = (const float*)d_in[12];

  char* ws = (char*)d_ws;
  constexpr size_t SZ_QKV = (size_t)B_ * L_ * D_ * 2;           // 8 MB
  constexpr size_t SZ_W   = (size_t)D_ * D_ * 2;                // 2 MB
  // pband/T (24 MB) aliases qb/kb/vb (all dead before flash)
  constexpr size_t OFF_PB = 0;                                  // NROW*192*2
  constexpr size_t OFF_QB = 0;
  constexpr size_t OFF_KB = OFF_QB + SZ_QKV;
  constexpr size_t OFF_VB = OFF_KB + SZ_QKV;
  constexpr size_t OFF_WQ = OFF_VB + SZ_QKV;                    // 24 MB
  constexpr size_t OFF_WK = OFF_WQ + SZ_W;
  constexpr size_t OFF_WV = OFF_WK + SZ_W;
  constexpr size_t OFF_QE = OFF_WV + SZ_W;                      // 30 MB, NROW*132*2
  constexpr size_t OFF_WO = OFF_QE + (size_t)NROW * QE_LD * 2;
  constexpr size_t OFF_EKP = OFF_WO + SZ_W;                     // 256*64*2
  constexpr size_t OFF_EVT = OFF_EKP + 256 * 64 * 2;            // 128*192*2
  constexpr size_t OFF_QP = OFF_EVT + 128 * PB_LD * 2;
  constexpr size_t OFF_KP = OFF_QP + SZ_QKV;
  constexpr size_t OFF_VP = OFF_KP + SZ_QKV;
  constexpr size_t OFF_VPT = OFF_VP + SZ_QKV;
  constexpr size_t OFF_MU = OFF_VPT + SZ_QKV;                   // NROW*4*4 = 1 MB
  constexpr size_t OFF_MS = OFF_MU + (size_t)NROW * 4 * 4;
  constexpr size_t OFF_LS = OFF_MS + (size_t)NROW * 4;
  constexpr size_t OFF_T0 = OFF_LS + (size_t)NROW * 4;
  constexpr size_t OFF_TMP = OFF_T0 + (size_t)NROW * 4;         // NROW*64*2

  auto U16 = [&](size_t off) { return (unsigned short*)(ws + off); };
  auto F32 = [&](size_t off) { return (float*)(ws + off); };

  // converts (merged launches)
  {
    ConvArgs a{};
    a.s[0] = q; a.s[1] = k; a.s[2] = v;
    a.d[0] = U16(OFF_QB); a.d[1] = U16(OFF_KB); a.d[2] = U16(OFF_VB);
    f32_to_bf16_multi<<<dim3(2048, 3), 256, 0, stream>>>(a, (B_ * L_ * D_) / 4);
    ConvArgs bargs{};
    bargs.s[0] = Wq; bargs.s[1] = Wk; bargs.s[2] = Wv; bargs.s[3] = Wo;
    bargs.d[0] = U16(OFF_WQ); bargs.d[1] = U16(OFF_WK); bargs.d[2] = U16(OFF_WV); bargs.d[3] = U16(OFF_WO);
    f32_to_bf16_multi<<<dim3(1024, 4), 256, 0, stream>>>(bargs, (D_ * D_) / 4);
  }
  build_ekev_k<<<96, 256, 0, stream>>>(Ek, Ev, U16(OFF_EKP), U16(OFF_EVT));

  // projections: qp/kp/vp = X @ W^T + b   (M=4096,N=1024,K=1024)
  gemm_bt<true, true, false><<<dim3(32, 8), 256, 0, stream>>>(
      U16(OFF_QB), U16(OFF_WQ), bq, U16(OFF_QP), 1024, 1024, 1024, 1024, 32);
  gemm_bt<true, true, false><<<dim3(32, 8), 256, 0, stream>>>(
      U16(OFF_KB), U16(OFF_WK), bk, U16(OFF_KP), 1024, 1024, 1024, 1024, 32);
  gemm_bt<true, true, false><<<dim3(32, 8), 256, 0, stream>>>(
      U16(OFF_VB), U16(OFF_WV), bv, U16(OFF_VP), 1024, 1024, 1024, 1024, 32);

  transpose_v_k<<<dim3(16, 64), 256, 0, stream>>>(U16(OFF_VP), U16(OFF_VPT));

  // qE = qp @ Ek^T  (M=65536,N=256(cut 129),K=64), bf16 out, ldc=132
  gemm_bt<true, false, false><<<dim3(512, 2), 256, 0, stream>>>(
      U16(OFF_QP), U16(OFF_EKP), nullptr, U16(OFF_QE), 64, 64, QE_LD, 129, 2);

  // fused attention (1D grid: bh = bid&63 keeps one bh's q-tiles on one XCD)
  flash_fwd_k<<<1024, 256, 0, stream>>>(
      U16(OFF_QP), U16(OFF_KP), U16(OFF_VPT), U16(OFF_QE),
      U16(OFF_PB), F32(OFF_MU), F32(OFF_MS), F32(OFF_LS), F32(OFF_T0), U16(OFF_TMP));

  // bucket matrix (in-place over pband) + out2 accumulate: tmp += T @ EvT
  build_T_k<<<16384, 256, 0, stream>>>(
      U16(OFF_PB), F32(OFF_MU), F32(OFF_MS), F32(OFF_LS), F32(OFF_T0));
  gemm_bt<true, false, true><<<dim3(512, 1), 256, 0, stream>>>(
      U16(OFF_PB), U16(OFF_EVT), nullptr, U16(OFF_TMP), PB_LD, PB_LD, 64, 64, 6);

  // out = tmp @ Wo^T + bo  (f32 out)
  gemm_bt<false, true, false><<<dim3(32, 8), 256, 0, stream>>>(
      U16(OFF_TMP), U16(OFF_WO), bo, (float*)d_out, 1024, 1024, 1024, 1024, 32);
}

// Round 4
// 147.136 us; speedup vs baseline: 2.8850x; 1.4821x over previous
//
#include <hip/hip_runtime.h>
#include <hip/hip_bf16.h>
#include <stdint.h>
#include <stddef.h>

#define B_ 4
#define L_ 1024
#define D_ 1024
#define H_ 16
#define HD_ 64
#define NROW 65536      // B*L*H
#define QE_LD 132       // qE row stride (bf16 elems)
#define EV_LD 192       // EvT row stride (= out2 MFMA K, 6 k-tiles of 32)
#define T_STR 200       // epilogue T row stride in LDS (u16; pad kills conflicts)

typedef __attribute__((ext_vector_type(8))) short bf16x8;
typedef __attribute__((ext_vector_type(4))) float f32x4;
typedef __attribute__((ext_vector_type(4))) unsigned short u16x4;

__device__ __forceinline__ float bf2f(unsigned short u) {
  union { unsigned int i; float f; } v; v.i = ((unsigned int)u) << 16; return v.f;
}
__device__ __forceinline__ unsigned short f2bf(float f) {
  union { float f; unsigned int i; } v; v.f = f;
  return (unsigned short)((v.i + 0x7fffu + ((v.i >> 16) & 1u)) >> 16);
}
__device__ __forceinline__ unsigned short f2bfrn(float f) {
  __hip_bfloat16 h = __float2bfloat16(f);
  return *reinterpret_cast<unsigned short*>(&h);
}
__device__ __forceinline__ void async16(const void* g, void* l) {
  __builtin_amdgcn_global_load_lds(
      (const __attribute__((address_space(1))) unsigned int*)g,
      (__attribute__((address_space(3))) unsigned int*)l, 16, 0, 0);
}

// ---------------------------------------------------------------------------
// f32 -> bf16 convert, multi-tensor (vectorized x4)
// ---------------------------------------------------------------------------
struct ConvArgs { const float* s[4]; unsigned short* d[4]; };

__global__ __launch_bounds__(256) void f32_to_bf16_multi(ConvArgs a, int n4) {
  const float* s = a.s[blockIdx.y];
  unsigned short* d = a.d[blockIdx.y];
  int i = blockIdx.x * 256 + threadIdx.x;
  int stride = gridDim.x * 256;
  for (; i < n4; i += stride) {
    float4 v = ((const float4*)s)[i];
    u16x4 o;
    o[0] = f2bf(v.x); o[1] = f2bf(v.y); o[2] = f2bf(v.z); o[3] = f2bf(v.w);
    ((u16x4*)d)[i] = o;
  }
}

// Build padded Ek (256x64 bf16, rows>=129 zero) and Ev^T padded (128x192 bf16,
// cols >=129 zero)
__global__ __launch_bounds__(256) void build_ekev_k(const float* __restrict__ Ek,
                                                    const float* __restrict__ Ev,
                                                    unsigned short* __restrict__ Ekp,
                                                    unsigned short* __restrict__ EvTp) {
  int i = blockIdx.x * 256 + threadIdx.x;
  if (i < 256 * 64) {
    int r = i >> 6, dd = i & 63;
    Ekp[i] = (r < 129) ? f2bf(Ek[r * 64 + dd]) : (unsigned short)0;
  }
  if (i < 128 * EV_LD) {
    int dd = i / EV_LD, r = i - dd * EV_LD;
    EvTp[i] = (dd < 64 && r < 129) ? f2bf(Ev[r * 64 + dd]) : (unsigned short)0;
  }
}

// ---------------------------------------------------------------------------
// GEMM: C[M,N] = A[M,K] * Bt[N,K]^T (+bias) ; bf16 in, f32 acc.
// Tile (MI*32)x128, BK=32, 4 waves, chunk-swizzled LDS, global_load_lds x16.
// z-batched: blockIdx.z selects pointer set (up to 3 independent GEMMs).
// ---------------------------------------------------------------------------
struct Gemm3 {
  const unsigned short* A[3];
  const unsigned short* Bt[3];
  const float* bias[3];
  void* C[3];
};

template<int MI, bool OBF16, bool BIAS>
__global__ __launch_bounds__(256) void gemm_bt(Gemm3 ga, int lda, int ldb, int ldc,
                                               int Ncut, int ktiles) {
  constexpr int BM = MI * 32;
  __shared__ unsigned short Al[2][BM * 32];
  __shared__ unsigned short Bl[2][128 * 32];
  const unsigned short* A = ga.A[blockIdx.z];
  const unsigned short* Bt = ga.Bt[blockIdx.z];
  const float* bias = ga.bias[blockIdx.z];
  void* Cv = ga.C[blockIdx.z];
  const int tid = threadIdx.x;
  const int w = tid >> 6, l = tid & 63;
  const int l15 = l & 15, lg = l >> 4;
  const int row0 = blockIdx.x * BM, col0 = blockIdx.y * 128;
  const int wm = (w >> 1) * (MI * 16), wn = (w & 1) * 64;

  f32x4 acc[MI][4];
#pragma unroll
  for (int i = 0; i < MI; ++i)
#pragma unroll
    for (int j = 0; j < 4; ++j) acc[i][j] = {0.f, 0.f, 0.f, 0.f};

  auto stage = [&](int buf, int kt) {
#pragma unroll
    for (int i = 0; i < MI / 2; ++i) {
      int p = (i * 4 + w) * 1024 + l * 16;   // byte offset within A tile
      int m = p >> 6;                        // tile-local row (64B rows)
      int clog = (l & 3) ^ ((m >> 1) & 3);   // logical k-chunk for this slot
      async16(A + (size_t)(row0 + m) * lda + kt * 32 + clog * 8,
              (char*)&Al[buf][0] + (i * 4 + w) * 1024);
    }
#pragma unroll
    for (int i = 0; i < 2; ++i) {
      int p = (i * 4 + w) * 1024 + l * 16;
      int m = p >> 6;
      int clog = (l & 3) ^ ((m >> 1) & 3);
      async16(Bt + (size_t)(col0 + m) * ldb + kt * 32 + clog * 8,
              (char*)&Bl[buf][0] + (i * 4 + w) * 1024);
    }
  };

  stage(0, 0);
  __syncthreads();
  for (int kt = 0; kt < ktiles; ++kt) {
    int cur = kt & 1;
    if (kt + 1 < ktiles) stage(cur ^ 1, kt + 1);
    bf16x8 af[MI], bfr[4];
#pragma unroll
    for (int mi = 0; mi < MI; ++mi) {
      int m = wm + mi * 16 + l15;
      af[mi] = *(const bf16x8*)&Al[cur][m * 32 + ((lg ^ ((m >> 1) & 3)) << 3)];
    }
#pragma unroll
    for (int ni = 0; ni < 4; ++ni) {
      int n = wn + ni * 16 + l15;
      bfr[ni] = *(const bf16x8*)&Bl[cur][n * 32 + ((lg ^ ((n >> 1) & 3)) << 3)];
    }
#pragma unroll
    for (int mi = 0; mi < MI; ++mi)
#pragma unroll
      for (int ni = 0; ni < 4; ++ni)
        acc[mi][ni] = __builtin_amdgcn_mfma_f32_16x16x32_bf16(af[mi], bfr[ni], acc[mi][ni], 0, 0, 0);
    __syncthreads();
  }

#pragma unroll
  for (int ni = 0; ni < 4; ++ni) {
    int col = col0 + wn + ni * 16 + l15;
    if (col < Ncut) {
      float bv = BIAS ? bias[col] : 0.f;
#pragma unroll
      for (int mi = 0; mi < MI; ++mi) {
        int rowb = row0 + wm + mi * 16 + lg * 4;
#pragma unroll
        for (int r = 0; r < 4; ++r) {
          float v = acc[mi][ni][r] + bv;
          size_t off = (size_t)(rowb + r) * ldc + col;
          if (OBF16) ((unsigned short*)Cv)[off] = f2bf(v);
          else       ((float*)Cv)[off] = v;
        }
      }
    }
  }
}

// ---------------------------------------------------------------------------
// Transpose vp (B,L,H,HD) -> vpT (B,H,HD,L), bf16
// ---------------------------------------------------------------------------
__global__ __launch_bounds__(256) void transpose_v_k(const unsigned short* __restrict__ vp,
                                                     unsigned short* __restrict__ vpT) {
  const int lt = blockIdx.x, bh = blockIdx.y;
  const int b = bh >> 4, h = bh & 15;
  __shared__ unsigned short tile[64][72];
  const int t = threadIdx.x;
#pragma unroll
  for (int j = 0; j < 2; ++j) {
    int lrow = (t >> 3) + 32 * j;
    int d0 = (t & 7) * 8;
    bf16x8 v = *(const bf16x8*)(vp + ((size_t)((b * L_ + lt * 64 + lrow) * H_ + h)) * HD_ + d0);
#pragma unroll
    for (int e = 0; e < 8; ++e) tile[lrow][d0 + e] = (unsigned short)v[e];
  }
  __syncthreads();
#pragma unroll
  for (int j = 0; j < 2; ++j) {
    int d = (t >> 3) + 32 * j;
    int l0 = (t & 7) * 8;
    bf16x8 o;
#pragma unroll
    for (int e = 0; e < 8; ++e) o[e] = (short)tile[l0 + e][d];
    *(bf16x8*)(vpT + ((size_t)((b * H_ + h) * HD_ + d)) * L_ + lt * 64 + l0) = o;
  }
}

// ---------------------------------------------------------------------------
// Fused flash attention + relative logits + FULL out2 (T @ EvT) in epilogue.
// Swapped QK^T (lane owns q-row), log2-domain softmax, defer-max THR=8.
// Band p's (3 tiles x 16/lane) kept in registers (static-indexed).
// Epilogue: per-wave T row (16 x 200 LDS, aliased over dead K/V buffers),
// 24 MFMA accumulate T @ EvT into O, then normalize+store.
// Grid: 1024 linear blocks, bh = bid&63 (XCD locality), qt = bid>>6.
// ---------------------------------------------------------------------------
__global__ __launch_bounds__(256, 3) void flash_fwd_k(
    const unsigned short* __restrict__ qp, const unsigned short* __restrict__ kp,
    const unsigned short* __restrict__ vpT, const unsigned short* __restrict__ qE,
    const unsigned short* __restrict__ EvTp, unsigned short* __restrict__ tmp) {
  __shared__ __align__(16) char smem[40960];
  unsigned short (*Kl)[4096] = (unsigned short (*)[4096])smem;
  unsigned short (*Vl)[4096] = (unsigned short (*)[4096])(smem + 16384);
  const int tid = threadIdx.x, w = tid >> 6, l = tid & 63;
  unsigned short* Plw = (unsigned short*)(smem + 32768) + w * 1024;
  const int l15 = l & 15, lg = l >> 4;
  const int bid = blockIdx.x;
  const int bh = bid & 63, qt = bid >> 6;
  const int b = bh >> 4, h = bh & 15;
  const int qw = qt * 64 + w * 16;
  const int q_lane = qw + l15;                 // this lane's q row
  const int rowbase = (b * L_ + qw) * H_ + h;
  const int rowi_lane = rowbase + l15 * H_;
  constexpr float C1 = 0.125f * 1.44269504f;   // scale * log2(e)

  // Q fragments (B-operand): col = q = qw + l15, k-chunk = ks*32 + lg*8
  bf16x8 qf[2];
  {
    const unsigned short* qrp = qp + (size_t)rowi_lane * HD_;
#pragma unroll
    for (int ks = 0; ks < 2; ++ks) qf[ks] = *(const bf16x8*)(qrp + ks * 32 + lg * 8);
  }
  const unsigned short* qerow = qE + (size_t)rowi_lane * QE_LD;
  const float qe0L = bf2f(qerow[0]) * C1;
  const float qe128L = bf2f(qerow[128]) * C1;

  f32x4 O[4];
#pragma unroll
  for (int nd = 0; nd < 4; ++nd) O[nd] = {0.f, 0.f, 0.f, 0.f};
  float mrow = -1e30f, lrow = 0.f, t0row = 0.f;   // mrow in log2-units

  // band state (static-indexed register arrays)
  u16x4 pks0[4], pks1[4], pks2[4];
  float mu0 = -1e30f, mu1 = -1e30f, mu2 = -1e30f;
  {
    u16x4 z4 = {0, 0, 0, 0};
#pragma unroll
    for (int ni = 0; ni < 4; ++ni) { pks0[ni] = z4; pks1[ni] = z4; pks2[ni] = z4; }
  }

  auto stage = [&](int buf, int kt) {
#pragma unroll
    for (int i = 0; i < 2; ++i) {
      int p = (i * 4 + w) * 1024 + l * 16;  // byte in 8KB tile (rows = 128B)
      int row = p >> 7;
      int clog = (l & 7) ^ (row & 7);
      async16(kp + ((size_t)((b * L_ + kt * 64 + row) * H_ + h)) * HD_ + clog * 8,
              (char*)&Kl[buf][0] + (i * 4 + w) * 1024);
      async16(vpT + ((size_t)((b * H_ + h) * HD_ + row)) * L_ + kt * 64 + clog * 8,
              (char*)&Vl[buf][0] + (i * 4 + w) * 1024);
    }
  };

  stage(0, 0);
  __syncthreads();

  for (int kt = 0; kt < 16; ++kt) {
    int cur = kt & 1;
    if (kt + 1 < 16) stage(cur ^ 1, kt + 1);

    // S^T = K * Q^T: lane col = q (l15), rows = k-local (ni*16 + lg*4 + r)
    f32x4 S[4];
#pragma unroll
    for (int ni = 0; ni < 4; ++ni) S[ni] = {0.f, 0.f, 0.f, 0.f};
#pragma unroll
    for (int ks = 0; ks < 2; ++ks) {
      bf16x8 kf[4];
#pragma unroll
      for (int ni = 0; ni < 4; ++ni) {
        int kk = ni * 16 + l15;
        kf[ni] = *(const bf16x8*)&Kl[cur][kk * 64 + (((ks * 4 + lg) ^ (kk & 7)) << 3)];
      }
#pragma unroll
      for (int ni = 0; ni < 4; ++ni)
        S[ni] = __builtin_amdgcn_mfma_f32_16x16x32_bf16(kf[ni], qf[ks], S[ni], 0, 0, 0);
    }

    const int cls = (kt <= qt - 2) ? 0 : ((kt >= qt + 2) ? 2 : 1);
    const int based = kt * 64 - q_lane;

    // logits in log2 domain
    if (cls == 1) {
#pragma unroll
      for (int ni = 0; ni < 4; ++ni)
#pragma unroll
        for (int r = 0; r < 4; ++r) {
          int delta = based + ni * 16 + lg * 4 + r;
          int idx = min(max(delta, -64), 64) + 64;
          S[ni][r] = S[ni][r] * C1 + bf2f(qerow[idx]) * C1;
        }
    } else {
      float qeL = (cls == 0) ? qe0L : qe128L;
#pragma unroll
      for (int ni = 0; ni < 4; ++ni)
#pragma unroll
        for (int r = 0; r < 4; ++r) S[ni][r] = S[ni][r] * C1 + qeL;
    }

    // row max: reg tree + 2 shuffles
    float x0 = fmaxf(fmaxf(S[0][0], S[0][1]), fmaxf(S[0][2], S[0][3]));
    float x1 = fmaxf(fmaxf(S[1][0], S[1][1]), fmaxf(S[1][2], S[1][3]));
    float x2 = fmaxf(fmaxf(S[2][0], S[2][1]), fmaxf(S[2][2], S[2][3]));
    float x3 = fmaxf(fmaxf(S[3][0], S[3][1]), fmaxf(S[3][2], S[3][3]));
    float pmax = fmaxf(fmaxf(x0, x1), fmaxf(x2, x3));
    pmax = fmaxf(pmax, __shfl_xor(pmax, 16));
    pmax = fmaxf(pmax, __shfl_xor(pmax, 32));

    // defer-max (THR = 8 nats = 11.54 log2-units)
    float a = 1.f;
    if (!__all(pmax <= mrow + 11.54f)) {
      float mnew = fmaxf(mrow, pmax);
      a = __builtin_amdgcn_exp2f(mrow - mnew);
      mrow = mnew;
      float aq0 = __shfl(a, lg * 4 + 0);
      float aq1 = __shfl(a, lg * 4 + 1);
      float aq2 = __shfl(a, lg * 4 + 2);
      float aq3 = __shfl(a, lg * 4 + 3);
#pragma unroll
      for (int nd = 0; nd < 4; ++nd) {
        O[nd][0] *= aq0; O[nd][1] *= aq1; O[nd][2] *= aq2; O[nd][3] *= aq3;
      }
    }

    // p = exp2(sL - mL)
#pragma unroll
    for (int ni = 0; ni < 4; ++ni)
#pragma unroll
      for (int r = 0; r < 4; ++r)
        S[ni][r] = __builtin_amdgcn_exp2f(S[ni][r] - mrow);

    float s0 = (S[0][0] + S[0][1]) + (S[0][2] + S[0][3]);
    float s1 = (S[1][0] + S[1][1]) + (S[1][2] + S[1][3]);
    float s2 = (S[2][0] + S[2][1]) + (S[2][2] + S[2][3]);
    float s3 = (S[3][0] + S[3][1]) + (S[3][2] + S[3][3]);
    float ps = (s0 + s1) + (s2 + s3);
    ps += __shfl_xor(ps, 16);
    ps += __shfl_xor(ps, 32);
    lrow = lrow * a + ps;

    if (cls == 0) {
      t0row = t0row * a + ps;
    } else if (cls == 2) {
      t0row = t0row * a;
    } else if (kt == qt - 1) {
      float p0 = 0.f;
#pragma unroll
      for (int ni = 0; ni < 4; ++ni)
#pragma unroll
        for (int r = 0; r < 4; ++r)
          if (based + ni * 16 + lg * 4 + r <= -64) p0 += S[ni][r];
      p0 += __shfl_xor(p0, 16);
      p0 += __shfl_xor(p0, 32);
      t0row = t0row * a + p0;
    } else {
      t0row = t0row * a;
    }

    // pack p to bf16; write Pl (per-wave, swizzled); save band tiles to regs
    u16x4 pcur[4];
#pragma unroll
    for (int ni = 0; ni < 4; ++ni) {
      u16x4 pk;
#pragma unroll
      for (int r = 0; r < 4; ++r) pk[r] = f2bfrn(S[ni][r]);
      pcur[ni] = pk;
      int slot = (ni * 2 + (lg >> 1)) ^ (l15 & 7);
      int addr = l15 * 64 + (slot << 3) + (lg & 1) * 4;
      *(u16x4*)&Plw[addr] = pk;
    }
    if (cls == 1) {
      if (kt == qt - 1) {
#pragma unroll
        for (int ni = 0; ni < 4; ++ni) pks0[ni] = pcur[ni];
        mu0 = mrow;
      } else if (kt == qt) {
#pragma unroll
        for (int ni = 0; ni < 4; ++ni) pks1[ni] = pcur[ni];
        mu1 = mrow;
      } else {
#pragma unroll
        for (int ni = 0; ni < 4; ++ni) pks2[ni] = pcur[ni];
        mu2 = mrow;
      }
    }

    // O += P * V  (Pl same-wave dep; Vl from barrier)
#pragma unroll
    for (int ks = 0; ks < 2; ++ks) {
      bf16x8 pf = *(const bf16x8*)&Plw[l15 * 64 + (((ks * 4 + lg) ^ (l15 & 7)) << 3)];
      bf16x8 vf[4];
#pragma unroll
      for (int nd = 0; nd < 4; ++nd) {
        int d = nd * 16 + l15;
        vf[nd] = *(const bf16x8*)&Vl[cur][d * 64 + (((ks * 4 + lg) ^ (d & 7)) << 3)];
      }
#pragma unroll
      for (int nd = 0; nd < 4; ++nd)
        O[nd] = __builtin_amdgcn_mfma_f32_16x16x32_bf16(pf, vf[nd], O[nd], 0, 0, 0);
    }
    __syncthreads();
  }

  // ---- epilogue: build unnormalized T row in LDS (over dead K/V), out2 MFMA ----
  unsigned short* Tl16 = (unsigned short*)smem + w * (16 * T_STR);
  {
    u16x4 z4 = {0, 0, 0, 0};
    u16x4* tl4 = (u16x4*)Tl16;
    for (int i = l; i < 16 * T_STR / 4; i += 64) tl4[i] = z4;
  }
  float bandsum = 0.f;
  auto addband = [&](const u16x4* pk, float muv, int btc) {
    float scale = __builtin_amdgcn_exp2f(muv - mrow);   // 0 for invalid tiles
    int jbase = (qt + btc - 1) * 64 + lg * 4 - q_lane + 64;
#pragma unroll
    for (int ni = 0; ni < 4; ++ni)
#pragma unroll
      for (int r = 0; r < 4; ++r) {
        int j = jbase + ni * 16 + r;
        if (j >= 1 && j <= 127) {
          float pf = bf2f((unsigned short)pk[ni][r]) * scale;
          Tl16[l15 * T_STR + j] = f2bfrn(pf);
          bandsum += pf;
        }
      }
  };
  addband(pks0, mu0, 0);
  addband(pks1, mu1, 1);
  addband(pks2, mu2, 2);
  bandsum += __shfl_xor(bandsum, 16);
  bandsum += __shfl_xor(bandsum, 32);
  if (lg == 0) {
    Tl16[l15 * T_STR] = f2bfrn(t0row);
    Tl16[l15 * T_STR + 128] = f2bfrn(fmaxf(0.f, lrow - t0row - bandsum));
  }
  // O += T @ EvT  (A = T from LDS, B = EvTp from global/L2; same C layout)
#pragma unroll
  for (int ks6 = 0; ks6 < 6; ++ks6) {
    bf16x8 af = *(const bf16x8*)(Tl16 + l15 * T_STR + ks6 * 32 + lg * 8);
    bf16x8 bfr[4];
#pragma unroll
    for (int nd = 0; nd < 4; ++nd)
      bfr[nd] = *(const bf16x8*)(EvTp + (size_t)(nd * 16 + l15) * EV_LD + ks6 * 32 + lg * 8);
#pragma unroll
    for (int nd = 0; nd < 4; ++nd)
      O[nd] = __builtin_amdgcn_mfma_f32_16x16x32_bf16(af, bfr[nd], O[nd], 0, 0, 0);
  }

  // normalize + store (out1 + out2)
  float invl = 1.f / lrow;
  float iq[4];
#pragma unroll
  for (int r = 0; r < 4; ++r) iq[r] = __shfl(invl, lg * 4 + r);
#pragma unroll
  for (int r = 0; r < 4; ++r) {
    size_t rowi = (size_t)(rowbase + (lg * 4 + r) * H_);
#pragma unroll
    for (int nd = 0; nd < 4; ++nd)
      tmp[rowi * HD_ + nd * 16 + l15] = f2bfrn(O[nd][r] * iq[r]);
  }
}

// ---------------------------------------------------------------------------
extern "C" void kernel_launch(void* const* d_in, const int* in_sizes, int n_in,
                              void* d_out, int out_size, void* d_ws, size_t ws_size,
                              hipStream_t stream) {
  (void)in_sizes; (void)n_in; (void)out_size; (void)ws_size;
  const float* q  = (const float*)d_in[0];
  const float* k  = (const float*)d_in[1];
  const float* v  = (const float*)d_in[2];
  const float* Wq = (const float*)d_in[3];
  const float* bq = (const float*)d_in[4];
  const float* Wk = (const float*)d_in[5];
  const float* bk = (const float*)d_in[6];
  const float* Wv = (const float*)d_in[7];
  const float* bv = (const float*)d_in[8];
  const float* Wo = (const float*)d_in[9];
  const float* bo = (const float*)d_in[10];
  const float* Ek = (const float*)d_in[11];
  const float* Ev = (const float*)d_in[12];

  char* ws = (char*)d_ws;
  constexpr size_t SZ_QKV = (size_t)B_ * L_ * D_ * 2;           // 8 MB
  constexpr size_t SZ_W   = (size_t)D_ * D_ * 2;                // 2 MB
  constexpr size_t OFF_QB = 0;
  constexpr size_t OFF_KB = OFF_QB + SZ_QKV;
  constexpr size_t OFF_VB = OFF_KB + SZ_QKV;
  constexpr size_t OFF_WQ = OFF_VB + SZ_QKV;
  constexpr size_t OFF_WK = OFF_WQ + SZ_W;
  constexpr size_t OFF_WV = OFF_WK + SZ_W;
  constexpr size_t OFF_QE = OFF_WV + SZ_W;                      // NROW*132*2
  constexpr size_t OFF_WO = OFF_QE + (size_t)NROW * QE_LD * 2;
  constexpr size_t OFF_EKP = OFF_WO + SZ_W;                     // 256*64*2
  constexpr size_t OFF_EVT = OFF_EKP + 256 * 64 * 2;            // 128*192*2
  constexpr size_t OFF_QP = OFF_EVT + 128 * EV_LD * 2;
  constexpr size_t OFF_KP = OFF_QP + SZ_QKV;
  constexpr size_t OFF_VP = OFF_KP + SZ_QKV;
  constexpr size_t OFF_VPT = OFF_VP + SZ_QKV;
  constexpr size_t OFF_TMP = OFF_VPT + SZ_QKV;                  // NROW*64*2

  auto U16 = [&](size_t off) { return (unsigned short*)(ws + off); };

  // converts (merged launches)
  {
    ConvArgs a{};
    a.s[0] = q; a.s[1] = k; a.s[2] = v;
    a.d[0] = U16(OFF_QB); a.d[1] = U16(OFF_KB); a.d[2] = U16(OFF_VB);
    f32_to_bf16_multi<<<dim3(2048, 3), 256, 0, stream>>>(a, (B_ * L_ * D_) / 4);
    ConvArgs bargs{};
    bargs.s[0] = Wq; bargs.s[1] = Wk; bargs.s[2] = Wv; bargs.s[3] = Wo;
    bargs.d[0] = U16(OFF_WQ); bargs.d[1] = U16(OFF_WK); bargs.d[2] = U16(OFF_WV); bargs.d[3] = U16(OFF_WO);
    f32_to_bf16_multi<<<dim3(1024, 4), 256, 0, stream>>>(bargs, (D_ * D_) / 4);
  }
  build_ekev_k<<<96, 256, 0, stream>>>(Ek, Ev, U16(OFF_EKP), U16(OFF_EVT));

  // projections qp/kp/vp = X @ W^T + b, z-batched (768 blocks = 3/CU)
  {
    Gemm3 g{};
    g.A[0] = U16(OFF_QB); g.Bt[0] = U16(OFF_WQ); g.bias[0] = bq; g.C[0] = U16(OFF_QP);
    g.A[1] = U16(OFF_KB); g.Bt[1] = U16(OFF_WK); g.bias[1] = bk; g.C[1] = U16(OFF_KP);
    g.A[2] = U16(OFF_VB); g.Bt[2] = U16(OFF_WV); g.bias[2] = bv; g.C[2] = U16(OFF_VP);
    gemm_bt<4, true, true><<<dim3(32, 8, 3), 256, 0, stream>>>(g, 1024, 1024, 1024, 1024, 32);
  }

  transpose_v_k<<<dim3(16, 64), 256, 0, stream>>>(U16(OFF_VP), U16(OFF_VPT));

  // qE = qp @ Ek^T  (M=65536, N cut 129, K=64), 64-row tiles -> 2048 blocks
  {
    Gemm3 g{};
    g.A[0] = U16(OFF_QP); g.Bt[0] = U16(OFF_EKP); g.bias[0] = nullptr; g.C[0] = U16(OFF_QE);
    gemm_bt<2, true, false><<<dim3(1024, 2, 1), 256, 0, stream>>>(g, 64, 64, QE_LD, 129, 2);
  }

  // fused attention (+ full out2 in epilogue)
  flash_fwd_k<<<1024, 256, 0, stream>>>(
      U16(OFF_QP), U16(OFF_KP), U16(OFF_VPT), U16(OFF_QE), U16(OFF_EVT), U16(OFF_TMP));

  // out = tmp @ Wo^T + bo  (f32 out), 64-row tiles -> 512 blocks
  {
    Gemm3 g{};
    g.A[0] = U16(OFF_TMP); g.Bt[0] = U16(OFF_WO); g.bias[0] = bo; g.C[0] = d_out;
    gemm_bt<2, false, true><<<dim3(64, 8, 1), 256, 0, stream>>>(g, 1024, 1024, 1024, 1024, 32);
  }
}